// Round 3
// baseline (12261.460 us; speedup 1.0000x reference)
//
#include <hip/hip_runtime.h>
#include <hip/hip_bf16.h>
#include <cstddef>

#define NN 100000
#define EE 3200000
static const float EF = 3200000.0f;

// ---------- helpers ----------

__device__ __forceinline__ float wsum(float v) {
  #pragma unroll
  for (int off = 32; off > 0; off >>= 1) v += __shfl_down(v, off, 64);
  return v;  // lane 0 holds wave total
}

// block-level reduce of 32 sums + 32 sumsq -> global atomics. red = shared float[256].
__device__ __forceinline__ void reduce64(float sum[32], float ssq[32], float* red,
                                         float* __restrict__ gsum, float* __restrict__ gssq) {
  const int wid = threadIdx.x >> 6, lane = threadIdx.x & 63;
  #pragma unroll
  for (int j = 0; j < 32; j++) {
    float a = wsum(sum[j]);
    float b = wsum(ssq[j]);
    if (lane == 0) { red[wid * 64 + j] = a; red[wid * 64 + 32 + j] = b; }
  }
  __syncthreads();
  if (threadIdx.x < 64) {
    float t = red[threadIdx.x] + red[64 + threadIdx.x] + red[128 + threadIdx.x] + red[192 + threadIdx.x];
    if (threadIdx.x < 32) unsafeAtomicAdd(&gsum[threadIdx.x], t);
    else                  unsafeAtomicAdd(&gssq[threadIdx.x - 32], t);
  }
}

__device__ __forceinline__ void loadrow(const float* __restrict__ xp, int s, float in[13]) {
  const float4* xr = reinterpret_cast<const float4*>(xp + (size_t)s * 12);
  float4 r0 = xr[0], r1 = xr[1], r2 = xr[2];
  in[0]=r0.x; in[1]=r0.y; in[2]=r0.z; in[3]=r0.w; in[4]=r1.x; in[5]=r1.y; in[6]=r1.z; in[7]=r1.w;
  in[8]=r2.x; in[9]=r2.y; in[10]=r2.z;
}

// ---------- setup kernels ----------

// w2tf[j][k] = d_j * w1b[k][j] (d_j = sign(g1b_j)); b1bf[j] = d_j*b1b[j];
// w2aT[j][0..42]+bias at 43; wpaT[j][0..10]+bias at 11
__global__ __launch_bounds__(256) void k_wprep(const float* __restrict__ w1b,
    const float* __restrict__ b1b, const float* __restrict__ g1b,
    const float* __restrict__ w2a, const float* __restrict__ b2a,
    const float* __restrict__ wpa, const float* __restrict__ bpa,
    float* __restrict__ w2tf, float* __restrict__ b1bf,
    float* __restrict__ w2aT, float* __restrict__ wpaT) {
  int t = threadIdx.x;
  for (int i = t; i < 1024; i += 256) {
    int j = i >> 5, k = i & 31;
    float d = (g1b[j] >= 0.f) ? 1.f : -1.f;
    w2tf[j * 32 + k] = d * w1b[k * 32 + j];
  }
  for (int i = t; i < 32 * 43; i += 256) { int j = i & 31, k = i >> 5; w2aT[j * 44 + k] = w2a[k * 32 + j]; }
  for (int i = t; i < 32 * 11; i += 256) { int j = i & 31, k = i >> 5; wpaT[j * 12 + k] = wpa[k * 32 + j]; }
  if (t < 32) {
    float d = (g1b[t] >= 0.f) ? 1.f : -1.f;
    b1bf[t] = d * b1b[t];
    w2aT[t * 44 + 43] = b2a[t];
    wpaT[t * 12 + 11] = bpa[t];
  }
}

// one edge pass (4 edges/thread/iter): dst counts, src out-degrees, per-src ea sums, global ea moments
__global__ __launch_bounds__(256) void k_prep(const int* __restrict__ dst, const int* __restrict__ src,
    const float* __restrict__ ea, int* __restrict__ cnt, int* __restrict__ deg,
    float* __restrict__ sea, float* __restrict__ cmom) {
  float p0 = 0, p1 = 0, p2 = 0, p3 = 0, p4 = 0;
  const int S = gridDim.x * 256;
  for (int g = blockIdx.x * 256 + threadIdx.x; g < EE / 4; g += S) {
    int4 d4 = reinterpret_cast<const int4*>(dst)[g];
    int4 s4 = reinterpret_cast<const int4*>(src)[g];
    float4 e0 = reinterpret_cast<const float4*>(ea)[2 * g];
    float4 e1 = reinterpret_cast<const float4*>(ea)[2 * g + 1];
    atomicAdd(&cnt[d4.x], 1); atomicAdd(&cnt[d4.y], 1); atomicAdd(&cnt[d4.z], 1); atomicAdd(&cnt[d4.w], 1);
    atomicAdd(&deg[s4.x], 1); atomicAdd(&deg[s4.y], 1); atomicAdd(&deg[s4.z], 1); atomicAdd(&deg[s4.w], 1);
    unsafeAtomicAdd(&sea[2 * s4.x], e0.x); unsafeAtomicAdd(&sea[2 * s4.x + 1], e0.y);
    unsafeAtomicAdd(&sea[2 * s4.y], e0.z); unsafeAtomicAdd(&sea[2 * s4.y + 1], e0.w);
    unsafeAtomicAdd(&sea[2 * s4.z], e1.x); unsafeAtomicAdd(&sea[2 * s4.z + 1], e1.y);
    unsafeAtomicAdd(&sea[2 * s4.w], e1.z); unsafeAtomicAdd(&sea[2 * s4.w + 1], e1.w);
    p0 += e0.x * e0.x + e0.z * e0.z + e1.x * e1.x + e1.z * e1.z;
    p1 += e0.x * e0.y + e0.z * e0.w + e1.x * e1.y + e1.z * e1.w;
    p2 += e0.y * e0.y + e0.w * e0.w + e1.y * e1.y + e1.w * e1.w;
    p3 += e0.x + e0.z + e1.x + e1.z;
    p4 += e0.y + e0.w + e1.y + e1.w;
  }
  p0 = wsum(p0); p1 = wsum(p1); p2 = wsum(p2); p3 = wsum(p3); p4 = wsum(p4);
  if ((threadIdx.x & 63) == 0) {
    unsafeAtomicAdd(&cmom[0], p0); unsafeAtomicAdd(&cmom[1], p1); unsafeAtomicAdd(&cmom[2], p2);
    unsafeAtomicAdd(&cmom[3], p3); unsafeAtomicAdd(&cmom[4], p4);
  }
}

__global__ __launch_bounds__(1024) void k_scan(const int* __restrict__ cnt,
                                               int* __restrict__ starts, int* __restrict__ fill) {
  __shared__ int part[1024];
  const int T = 1024, CH = (NN + T - 1) / T;
  int t = threadIdx.x;
  int lo = t * CH, hi = min(lo + CH, NN);
  int s = 0;
  for (int i = lo; i < hi; i++) s += cnt[i];
  part[t] = s; __syncthreads();
  for (int off = 1; off < T; off <<= 1) {
    int v = (t >= off) ? part[t - off] : 0;
    __syncthreads();
    part[t] += v;
    __syncthreads();
  }
  int run = part[t] - s;  // exclusive prefix
  for (int i = lo; i < hi; i++) { starts[i] = run; fill[i] = run; run += cnt[i]; }
  if (t == T - 1) starts[NN] = EE;
}

// scatter packed 16B edge records (src, ea.x, ea.y, 0) into CSR order
__global__ __launch_bounds__(256) void k_scatter(const int* __restrict__ dst, const int* __restrict__ src,
    const float* __restrict__ ea, int* __restrict__ fill, int4* __restrict__ edg) {
  const int S = gridDim.x * 256;
  for (int g = blockIdx.x * 256 + threadIdx.x; g < EE / 4; g += S) {
    int4 d4 = reinterpret_cast<const int4*>(dst)[g];
    int4 s4 = reinterpret_cast<const int4*>(src)[g];
    float4 e0 = reinterpret_cast<const float4*>(ea)[2 * g];
    float4 e1 = reinterpret_cast<const float4*>(ea)[2 * g + 1];
    int p0 = atomicAdd(&fill[d4.x], 1);
    edg[p0] = make_int4(s4.x, __float_as_int(e0.x), __float_as_int(e0.y), 0);
    int p1 = atomicAdd(&fill[d4.y], 1);
    edg[p1] = make_int4(s4.y, __float_as_int(e0.z), __float_as_int(e0.w), 0);
    int p2 = atomicAdd(&fill[d4.z], 1);
    edg[p2] = make_int4(s4.z, __float_as_int(e1.x), __float_as_int(e1.y), 0);
    int p3 = atomicAdd(&fill[d4.w], 1);
    edg[p3] = make_int4(s4.w, __float_as_int(e1.z), __float_as_int(e1.w), 0);
  }
}

// padded node rows: xp[n][0..9]=x cols 0..9, [10]=x col10 (current), [11]=0
__global__ __launch_bounds__(256) void k_xp(const float* __restrict__ x, float* __restrict__ xp) {
  int n = blockIdx.x * 256 + threadIdx.x;
  if (n >= NN) return;
  float v[11];
  #pragma unroll
  for (int k = 0; k < 11; k++) v[k] = x[(size_t)n * 11 + k];
  float4* o = reinterpret_cast<float4*>(xp + (size_t)n * 12);
  o[0] = make_float4(v[0], v[1], v[2], v[3]);
  o[1] = make_float4(v[4], v[5], v[6], v[7]);
  o[2] = make_float4(v[8], v[9], v[10], 0.f);
}

// ---------- per-conv: input moments (node pass, replaces a P1 edge pass) ----------
// mom layout: [0..10]=S_x (deg-weighted), [11..76]=sxx upper-tri(11), [77..98]=sxe
__global__ __launch_bounds__(256) void k_mom(const float* __restrict__ xp, const int* __restrict__ deg,
                                             const float* __restrict__ sea, float* __restrict__ mom) {
  const int n = blockIdx.x * 256 + threadIdx.x;
  const int lane = threadIdx.x & 63;
  float v[11]; float w = 0.f; float sx = 0.f, sy = 0.f;
  #pragma unroll
  for (int k = 0; k < 11; k++) v[k] = 0.f;
  if (n < NN) {
    w = (float)deg[n];
    loadrow(xp, n, v);
    sx = sea[2 * n]; sy = sea[2 * n + 1];
  }
  int ch = 0;
  #pragma unroll
  for (int a = 0; a < 11; a++) {
    float r = wsum(w * v[a]);
    if (lane == 0) unsafeAtomicAdd(&mom[ch], r);
    ch++;
  }
  #pragma unroll
  for (int a = 0; a < 11; a++) {
    #pragma unroll
    for (int b = a; b < 11; b++) {
      float r = wsum(w * v[a] * v[b]);
      if (lane == 0) unsafeAtomicAdd(&mom[ch], r);
      ch++;
    }
  }
  #pragma unroll
  for (int a = 0; a < 11; a++) {
    float rx = wsum(v[a] * sx);
    if (lane == 0) unsafeAtomicAdd(&mom[ch], rx);
    ch++;
    float ry = wsum(v[a] * sy);
    if (lane == 0) unsafeAtomicAdd(&mom[ch], ry);
    ch++;
  }
}

__device__ __forceinline__ float msym(const float* mom, const float* cmom, int k, int l) {
  int a = min(k, l), b = max(k, l);
  if (b < 11) return mom[11 + a * 11 - a * (a - 1) / 2 + (b - a)];
  if (a < 11) return mom[77 + a * 2 + (b - 11)];
  return cmom[(a - 11) + (b - 11)];
}

// layer-1 BN params from moments; emit FOLDED transposed weights w1f[j][0..12]+bias[13]; zero mom.
__global__ void k_fin1(float* __restrict__ mom, const float* __restrict__ cmom,
    const float* __restrict__ w1a, const float* __restrict__ b1a,
    const float* __restrict__ g1a, const float* __restrict__ be1a,
    float* __restrict__ w1f) {
  int j = threadIdx.x;  // 32 threads
  float w[13], S[13];
  #pragma unroll
  for (int k = 0; k < 13; k++) w[k] = w1a[k * 32 + j];
  #pragma unroll
  for (int k = 0; k < 11; k++) S[k] = mom[k];
  S[11] = cmom[3]; S[12] = cmom[4];
  float lin = 0.f;
  #pragma unroll
  for (int k = 0; k < 13; k++) lin = fmaf(w[k], S[k], lin);
  float quad = 0.f;
  #pragma unroll
  for (int k = 0; k < 13; k++)
    #pragma unroll
    for (int l = 0; l < 13; l++) quad = fmaf(w[k] * w[l], msym(mom, cmom, k, l), quad);
  const float invE = 1.f / EF;
  float b = b1a[j];
  float mean = fmaf(lin, invE, b);
  float ey2 = (quad + 2.f * b * lin) * invE + b * b;
  float var = fmaxf(ey2 - mean * mean, 0.f);
  float A = g1a[j] * rsqrtf(var + 1e-5f);
  float C = be1a[j] - mean * A;
  #pragma unroll
  for (int k = 0; k < 13; k++) w1f[j * 16 + k] = A * w[k];
  w1f[j * 16 + 13] = fmaf(A, b, C);
  w1f[j * 16 + 14] = 0.f; w1f[j * 16 + 15] = 0.f;
  __syncthreads();
  for (int i = j; i < 128; i += 32) mom[i] = 0.f;
}

// ---------- fused edge pass: MLP1 -> per-node max of d*z + Σm, Σz² stats ----------

__device__ __forceinline__ void mlp1_pair(const float inA[13], const float inB[13],
    const float* __restrict__ w1f, float mA[32], float mB[32], float ms[32]) {
  #pragma unroll
  for (int j = 0; j < 32; j++) {
    const float* wr = w1f + j * 16;
    float aA = wr[13], aB = wr[13];
    #pragma unroll
    for (int k = 0; k < 13; k++) { aA = fmaf(inA[k], wr[k], aA); aB = fmaf(inB[k], wr[k], aB); }
    aA = fmaxf(aA, 0.f); aB = fmaxf(aB, 0.f);
    mA[j] = aA; mB[j] = aB; ms[j] += aA + aB;
  }
}

__global__ __launch_bounds__(256) void k_fusedagg(
    const int* __restrict__ starts, const int4* __restrict__ edg,
    const float* __restrict__ xp, const float* __restrict__ w1f,
    const float* __restrict__ w2tf, const float* __restrict__ b1bf,
    float* __restrict__ tzb, float* __restrict__ gms, float* __restrict__ gzq) {
  __shared__ float red[256];
  const int t = blockIdx.x * 256 + threadIdx.x;
  const int n = t >> 2, q = t & 3;
  float tz[32], zq[32], ms[32];
  #pragma unroll
  for (int j = 0; j < 32; j++) { tz[j] = -3.0e38f; zq[j] = 0.f; ms[j] = 0.f; }
  int lo = 0, hi = 0;
  if (n < NN) { lo = starts[n]; hi = starts[n + 1]; }
  int sl = lo + q;
  for (; sl + 4 < hi; sl += 8) {      // two assigned edges: sl and sl+4
    int4 rA = edg[sl], rB = edg[sl + 4];
    float inA[13], inB[13];
    loadrow(xp, rA.x, inA); inA[11] = __int_as_float(rA.y); inA[12] = __int_as_float(rA.z);
    loadrow(xp, rB.x, inB); inB[11] = __int_as_float(rB.y); inB[12] = __int_as_float(rB.z);
    float mA[32], mB[32];
    mlp1_pair(inA, inB, w1f, mA, mB, ms);
    #pragma unroll
    for (int j = 0; j < 32; j++) {
      const float* wr = w2tf + j * 32;
      float zA = b1bf[j], zB = b1bf[j];
      #pragma unroll
      for (int k = 0; k < 32; k++) { zA = fmaf(mA[k], wr[k], zA); zB = fmaf(mB[k], wr[k], zB); }
      tz[j] = fmaxf(tz[j], fmaxf(zA, zB));
      zq[j] = fmaf(zA, zA, zq[j]);
      zq[j] = fmaf(zB, zB, zq[j]);
    }
  }
  if (sl < hi) {                      // single tail edge
    int4 rA = edg[sl];
    float inA[13];
    loadrow(xp, rA.x, inA); inA[11] = __int_as_float(rA.y); inA[12] = __int_as_float(rA.z);
    float mA[32];
    #pragma unroll
    for (int j = 0; j < 32; j++) {
      const float* wr = w1f + j * 16;
      float a = wr[13];
      #pragma unroll
      for (int k = 0; k < 13; k++) a = fmaf(inA[k], wr[k], a);
      a = fmaxf(a, 0.f);
      mA[j] = a; ms[j] += a;
    }
    #pragma unroll
    for (int j = 0; j < 32; j++) {
      const float* wr = w2tf + j * 32;
      float z = b1bf[j];
      #pragma unroll
      for (int k = 0; k < 32; k++) z = fmaf(mA[k], wr[k], z);
      tz[j] = fmaxf(tz[j], z);
      zq[j] = fmaf(z, z, zq[j]);
    }
  }
  #pragma unroll
  for (int j = 0; j < 32; j++) {
    tz[j] = fmaxf(tz[j], __shfl_xor(tz[j], 1, 64));
    tz[j] = fmaxf(tz[j], __shfl_xor(tz[j], 2, 64));
  }
  if (q == 0 && n < NN) {
    float4* ot = reinterpret_cast<float4*>(tzb + (size_t)n * 32);
    #pragma unroll
    for (int j = 0; j < 8; j++)
      ot[j] = make_float4(tz[4 * j], tz[4 * j + 1], tz[4 * j + 2], tz[4 * j + 3]);
  }
  reduce64(ms, zq, red, gms, gzq);
}

// layer-2 BN: zs_j = w1b[:,j]·ms + E*b1b_j; A2d = A2*sign(g1b); zero ms/zq
__global__ void k_fin2(float* __restrict__ ms, float* __restrict__ zq,
    const float* __restrict__ w1b, const float* __restrict__ b1b,
    const float* __restrict__ g1b, const float* __restrict__ be1b,
    float* __restrict__ A2d, float* __restrict__ C2) {
  __shared__ float sm[32];
  int j = threadIdx.x;  // 32 threads
  sm[j] = ms[j];
  __syncthreads();
  float zs = EF * b1b[j];
  #pragma unroll
  for (int k = 0; k < 32; k++) zs = fmaf(w1b[k * 32 + j], sm[k], zs);
  const float invE = 1.f / EF;
  float mu = zs * invE;
  float var = fmaxf(zq[j] * invE - mu * mu, 0.f);
  float A = g1b[j] * rsqrtf(var + 1e-5f);
  float C = be1b[j] - mu * A;
  float d = (g1b[j] >= 0.f) ? 1.f : -1.f;
  A2d[j] = A * d; C2[j] = C;
  ms[j] = 0.f; zq[j] = 0.f;
}

// BN finalize: a = g*rsqrt(var+eps), c = be - mu*a; zero sums for reuse
__global__ void k_finalize(float* __restrict__ sum, float* __restrict__ ssq,
                           const float* __restrict__ g, const float* __restrict__ be,
                           float inv_n, int ncols, float* __restrict__ a, float* __restrict__ c) {
  int j = threadIdx.x;
  if (j < ncols) {
    float mu = sum[j] * inv_n;
    float var = fmaxf(ssq[j] * inv_n - mu * mu, 0.f);
    float s = rsqrtf(var + 1e-5f) * g[j];
    a[j] = s; c[j] = be[j] - mu * s;
    sum[j] = 0.f; ssq[j] = 0.f;
  }
}

// ---------- agg finalize + h_pre = [x, agg] @ w2a + b2a (+stats) ----------

__global__ __launch_bounds__(256) void k_hpre2(const float* __restrict__ xp,
    const float* __restrict__ tzb, const int* __restrict__ starts,
    const float* __restrict__ A2d, const float* __restrict__ C2, const float* __restrict__ w2aT,
    float* __restrict__ hpre, float* __restrict__ gsum, float* __restrict__ gssq) {
  __shared__ float red[256];
  const int n = blockIdx.x * 256 + threadIdx.x;
  float h[32], hh[32];
  #pragma unroll
  for (int j = 0; j < 32; j++) h[j] = 0.f;
  if (n < NN) {
    float xv[11];
    loadrow(xp, n, xv);
    const int dg = starts[n + 1] - starts[n];
    float av[32];
    if (dg > 0) {
      const float4* tp = reinterpret_cast<const float4*>(tzb + (size_t)n * 32);
      #pragma unroll
      for (int j = 0; j < 8; j++) {
        float4 v = tp[j];
        av[4 * j]     = fmaxf(0.f, fmaf(A2d[4 * j],     v.x, C2[4 * j]));
        av[4 * j + 1] = fmaxf(0.f, fmaf(A2d[4 * j + 1], v.y, C2[4 * j + 1]));
        av[4 * j + 2] = fmaxf(0.f, fmaf(A2d[4 * j + 2], v.z, C2[4 * j + 2]));
        av[4 * j + 3] = fmaxf(0.f, fmaf(A2d[4 * j + 3], v.w, C2[4 * j + 3]));
      }
    } else {
      #pragma unroll
      for (int j = 0; j < 32; j++) av[j] = 0.f;
    }
    #pragma unroll
    for (int j = 0; j < 32; j++) {
      const float* wr = w2aT + j * 44;
      float acc = wr[43];
      #pragma unroll
      for (int k = 0; k < 11; k++) acc = fmaf(xv[k], wr[k], acc);
      #pragma unroll
      for (int k = 0; k < 32; k++) acc = fmaf(av[k], wr[11 + k], acc);
      h[j] = acc;
    }
    float4* hp = reinterpret_cast<float4*>(hpre + (size_t)n * 32);
    #pragma unroll
    for (int j = 0; j < 8; j++)
      hp[j] = make_float4(h[4 * j], h[4 * j + 1], h[4 * j + 2], h[4 * j + 3]);
  }
  #pragma unroll
  for (int j = 0; j < 32; j++) hh[j] = h[j] * h[j];
  reduce64(h, hh, red, gsum, gssq);
}

// comb = relu(relu(bn(h_pre)) @ w2b + b2b) -> xp col 10
__global__ __launch_bounds__(256) void k_comb(const float* __restrict__ hpre,
    const float* __restrict__ a3, const float* __restrict__ c3,
    const float* __restrict__ w2b, const float* __restrict__ b2b, float* __restrict__ xp) {
  const int n = blockIdx.x * 256 + threadIdx.x;
  if (n >= NN) return;
  const float4* hp = reinterpret_cast<const float4*>(hpre + (size_t)n * 32);
  float acc = b2b[0];
  #pragma unroll
  for (int j = 0; j < 8; j++) {
    float4 v = hp[j];
    acc += fmaxf(0.f, fmaf(v.x, a3[4 * j],     c3[4 * j]))     * w2b[4 * j];
    acc += fmaxf(0.f, fmaf(v.y, a3[4 * j + 1], c3[4 * j + 1])) * w2b[4 * j + 1];
    acc += fmaxf(0.f, fmaf(v.z, a3[4 * j + 2], c3[4 * j + 2])) * w2b[4 * j + 2];
    acc += fmaxf(0.f, fmaf(v.w, a3[4 * j + 3], c3[4 * j + 3])) * w2b[4 * j + 3];
  }
  xp[(size_t)n * 12 + 10] = fmaxf(acc, 0.f);
}

// ---------- power MLP ----------

// yp = x @ wpa + bpa : store to ybuf + stats
__global__ __launch_bounds__(256) void k_p5(const float* __restrict__ xp, const float* __restrict__ wpaT,
                                            float* __restrict__ ybuf,
                                            float* __restrict__ gsum, float* __restrict__ gssq) {
  __shared__ float red[256];
  const int n = blockIdx.x * 256 + threadIdx.x;
  float y[32], yy[32];
  #pragma unroll
  for (int j = 0; j < 32; j++) y[j] = 0.f;
  if (n < NN) {
    float xv[11];
    loadrow(xp, n, xv);
    #pragma unroll
    for (int j = 0; j < 32; j++) {
      const float* wr = wpaT + j * 12;
      float acc = wr[11];
      #pragma unroll
      for (int k = 0; k < 11; k++) acc = fmaf(xv[k], wr[k], acc);
      y[j] = acc;
    }
    float4* yp = reinterpret_cast<float4*>(ybuf + (size_t)n * 32);
    #pragma unroll
    for (int j = 0; j < 8; j++)
      yp[j] = make_float4(y[4 * j], y[4 * j + 1], y[4 * j + 2], y[4 * j + 3]);
  }
  #pragma unroll
  for (int j = 0; j < 32; j++) yy[j] = y[j] * y[j];
  reduce64(y, yy, red, gsum, gssq);
}

// yq = relu(bn(yp)) @ wpb + bpb : store + scalar stats (reads stored yp)
__global__ __launch_bounds__(256) void k_p6(const float* __restrict__ ybuf,
    const float* __restrict__ a4, const float* __restrict__ c4,
    const float* __restrict__ wpb, const float* __restrict__ bpb,
    float* __restrict__ yq, float* __restrict__ gsum, float* __restrict__ gssq) {
  __shared__ float red[8];
  const int n = blockIdx.x * 256 + threadIdx.x;
  float sum = 0.f, ssq = 0.f;
  if (n < NN) {
    const float4* yp = reinterpret_cast<const float4*>(ybuf + (size_t)n * 32);
    float q = bpb[0];
    #pragma unroll
    for (int j = 0; j < 8; j++) {
      float4 v = yp[j];
      q = fmaf(fmaxf(0.f, fmaf(v.x, a4[4 * j],     c4[4 * j])),     wpb[4 * j],     q);
      q = fmaf(fmaxf(0.f, fmaf(v.y, a4[4 * j + 1], c4[4 * j + 1])), wpb[4 * j + 1], q);
      q = fmaf(fmaxf(0.f, fmaf(v.z, a4[4 * j + 2], c4[4 * j + 2])), wpb[4 * j + 2], q);
      q = fmaf(fmaxf(0.f, fmaf(v.w, a4[4 * j + 3], c4[4 * j + 3])), wpb[4 * j + 3], q);
    }
    yq[n] = q;
    sum = q; ssq = q * q;
  }
  float s = wsum(sum), qq = wsum(ssq);
  const int wid = threadIdx.x >> 6, lane = threadIdx.x & 63;
  if (lane == 0) { red[wid] = s; red[4 + wid] = qq; }
  __syncthreads();
  if (threadIdx.x == 0) {
    unsafeAtomicAdd(&gsum[0], red[0] + red[1] + red[2] + red[3]);
    unsafeAtomicAdd(&gssq[0], red[4] + red[5] + red[6] + red[7]);
  }
}

__global__ __launch_bounds__(256) void k_p7(const float* __restrict__ yq,
    const float* __restrict__ a5, const float* __restrict__ c5, float* __restrict__ out) {
  int n = blockIdx.x * 256 + threadIdx.x;
  if (n < NN) out[n] = fmaxf(0.f, fmaf(yq[n], a5[0], c5[0]));
}

// ---------- host launch ----------

extern "C" void kernel_launch(void* const* d_in, const int* in_sizes, int n_in,
                              void* d_out, int out_size, void* d_ws, size_t ws_size,
                              hipStream_t stream) {
  const float* x    = (const float*)d_in[0];
  const float* ea   = (const float*)d_in[1];
  const int*   ei   = (const int*)d_in[2];
  const int*   srcp = ei;
  const int*   dstp = ei + EE;
  const float* w1a = (const float*)d_in[3],  *b1a = (const float*)d_in[4];
  const float* g1a = (const float*)d_in[5],  *be1a = (const float*)d_in[6];
  const float* w1b = (const float*)d_in[7],  *b1b = (const float*)d_in[8];
  const float* g1b = (const float*)d_in[9],  *be1b = (const float*)d_in[10];
  const float* w2a = (const float*)d_in[11], *b2a = (const float*)d_in[12];
  const float* g2a = (const float*)d_in[13], *be2a = (const float*)d_in[14];
  const float* w2b = (const float*)d_in[15], *b2b = (const float*)d_in[16];
  const float* wpa = (const float*)d_in[17], *bpa = (const float*)d_in[18];
  const float* gpa = (const float*)d_in[19], *bepa = (const float*)d_in[20];
  const float* wpb = (const float*)d_in[21], *bpb = (const float*)d_in[22];
  const float* gpb = (const float*)d_in[23], *bepb = (const float*)d_in[24];

  size_t off = 0;
  char* base = (char*)d_ws;
  auto alloc = [&](size_t bytes) -> void* {
    void* p = base + off;
    off += (bytes + 255) & ~(size_t)255;
    return p;
  };
  float* stats = (float*)alloc(2048);
  float* coef  = (float*)alloc(2048);
  float* mom   = (float*)alloc(512);
  float* cmom  = (float*)alloc(256);
  float* w1f   = (float*)alloc(16 * 32 * 4);
  float* w2tf  = (float*)alloc(32 * 32 * 4);
  float* b1bf  = (float*)alloc(256);
  float* w2aT  = (float*)alloc(32 * 44 * 4);
  float* wpaT  = (float*)alloc(32 * 12 * 4);
  int*   cnt    = (int*)alloc(NN * 4);
  int*   deg    = (int*)alloc(NN * 4);
  float* sea    = (float*)alloc((size_t)NN * 2 * 4);
  int*   starts = (int*)alloc((NN + 1) * 4);
  int*   fill   = (int*)alloc(NN * 4);
  int4*  edg    = (int4*)alloc((size_t)EE * 16);
  float* xp     = (float*)alloc((size_t)NN * 12 * 4);
  float* tzb    = (float*)alloc((size_t)NN * 32 * 4);
  float* hpre   = (float*)alloc((size_t)NN * 32 * 4);
  float* yq     = (float*)alloc(NN * 4);

  float *MS2  = stats,       *ZQ2  = stats + 32;
  float *SUM3 = stats + 64,  *SSQ3 = stats + 96;
  float *SUM4 = stats + 128, *SSQ4 = stats + 160;
  float *SUM5 = stats + 192, *SSQ5 = stats + 224;
  float *A2d = coef,       *C2 = coef + 32;
  float *A3  = coef + 64,  *C3 = coef + 96;
  float *A4  = coef + 128, *C4 = coef + 160;
  float *A5  = coef + 192, *C5 = coef + 224;

  hipMemsetAsync(stats, 0, 2048, stream);
  hipMemsetAsync(mom, 0, 512 + 256, stream);   // mom + cmom
  hipMemsetAsync(cnt, 0, NN * 4, stream);
  hipMemsetAsync(deg, 0, NN * 4, stream);
  hipMemsetAsync(sea, 0, (size_t)NN * 2 * 4, stream);

  const int GN = (NN + 255) / 256;          // 391
  const int GA = (4 * NN + 255) / 256;      // 1563
  const int GE4 = (EE / 4 + 255) / 256;     // 3125

  k_wprep  <<<1, 256, 0, stream>>>(w1b, b1b, g1b, w2a, b2a, wpa, bpa, w2tf, b1bf, w2aT, wpaT);
  k_prep   <<<GE4, 256, 0, stream>>>(dstp, srcp, ea, cnt, deg, sea, cmom);
  k_scan   <<<1, 1024, 0, stream>>>(cnt, starts, fill);
  k_scatter<<<GE4, 256, 0, stream>>>(dstp, srcp, ea, fill, edg);
  k_xp     <<<GN, 256, 0, stream>>>(x, xp);

  const float invN = 1.f / (float)NN;
  for (int c = 0; c < 3; c++) {
    k_mom     <<<GN, 256, 0, stream>>>(xp, deg, sea, mom);
    k_fin1    <<<1, 32, 0, stream>>>(mom, cmom, w1a, b1a, g1a, be1a, w1f);
    k_fusedagg<<<GA, 256, 0, stream>>>(starts, edg, xp, w1f, w2tf, b1bf, tzb, MS2, ZQ2);
    k_fin2    <<<1, 32, 0, stream>>>(MS2, ZQ2, w1b, b1b, g1b, be1b, A2d, C2);
    k_hpre2   <<<GN, 256, 0, stream>>>(xp, tzb, starts, A2d, C2, w2aT, hpre, SUM3, SSQ3);
    k_finalize<<<1, 32, 0, stream>>>(SUM3, SSQ3, g2a, be2a, invN, 32, A3, C3);
    k_comb    <<<GN, 256, 0, stream>>>(hpre, A3, C3, w2b, b2b, xp);
  }

  k_p5      <<<GN, 256, 0, stream>>>(xp, wpaT, hpre, SUM4, SSQ4);
  k_finalize<<<1, 32, 0, stream>>>(SUM4, SSQ4, gpa, bepa, invN, 32, A4, C4);
  k_p6      <<<GN, 256, 0, stream>>>(hpre, A4, C4, wpb, bpb, yq, SUM5, SSQ5);
  k_finalize<<<1, 32, 0, stream>>>(SUM5, SSQ5, gpb, bepb, invN, 1, A5, C5);
  k_p7      <<<GN, 256, 0, stream>>>(yq, A5, C5, (float*)d_out);
}

// Round 4
// 9569.704 us; speedup vs baseline: 1.2813x; 1.2813x over previous
//
#include <hip/hip_runtime.h>
#include <hip/hip_bf16.h>
#include <cstddef>

#define NN 100000
#define EE 3200000
static const float EF = 3200000.0f;

// ---------- helpers ----------

__device__ __forceinline__ float wsum(float v) {
  #pragma unroll
  for (int off = 32; off > 0; off >>= 1) v += __shfl_down(v, off, 64);
  return v;  // lane 0 holds wave total
}

// block-level reduce of 32 sums + 32 sumsq -> global atomics. red = shared float[256].
__device__ __forceinline__ void reduce64(float sum[32], float ssq[32], float* red,
                                         float* __restrict__ gsum, float* __restrict__ gssq) {
  const int wid = threadIdx.x >> 6, lane = threadIdx.x & 63;
  #pragma unroll
  for (int j = 0; j < 32; j++) {
    float a = wsum(sum[j]);
    float b = wsum(ssq[j]);
    if (lane == 0) { red[wid * 64 + j] = a; red[wid * 64 + 32 + j] = b; }
  }
  __syncthreads();
  if (threadIdx.x < 64) {
    float t = red[threadIdx.x] + red[64 + threadIdx.x] + red[128 + threadIdx.x] + red[192 + threadIdx.x];
    if (threadIdx.x < 32) unsafeAtomicAdd(&gsum[threadIdx.x], t);
    else                  unsafeAtomicAdd(&gssq[threadIdx.x - 32], t);
  }
}

__device__ __forceinline__ void loadrow(const float* __restrict__ xp, int s, float in[13]) {
  const float4* xr = reinterpret_cast<const float4*>(xp + (size_t)s * 12);
  float4 r0 = xr[0], r1 = xr[1], r2 = xr[2];
  in[0]=r0.x; in[1]=r0.y; in[2]=r0.z; in[3]=r0.w; in[4]=r1.x; in[5]=r1.y; in[6]=r1.z; in[7]=r1.w;
  in[8]=r2.x; in[9]=r2.y; in[10]=r2.z;
}

// ---------- setup kernels ----------

// w2tf[j][k] = d_j * w1b[k][j] (d_j = sign(g1b_j)); b1bf[j] = d_j*b1b[j];
// w2aT[j][0..42]+bias at 43; wpaT[j][0..10]+bias at 11
__global__ __launch_bounds__(256) void k_wprep(const float* __restrict__ w1b,
    const float* __restrict__ b1b, const float* __restrict__ g1b,
    const float* __restrict__ w2a, const float* __restrict__ b2a,
    const float* __restrict__ wpa, const float* __restrict__ bpa,
    float* __restrict__ w2tf, float* __restrict__ b1bf,
    float* __restrict__ w2aT, float* __restrict__ wpaT) {
  int t = threadIdx.x;
  for (int i = t; i < 1024; i += 256) {
    int j = i >> 5, k = i & 31;
    float d = (g1b[j] >= 0.f) ? 1.f : -1.f;
    w2tf[j * 32 + k] = d * w1b[k * 32 + j];
  }
  for (int i = t; i < 32 * 43; i += 256) { int j = i & 31, k = i >> 5; w2aT[j * 44 + k] = w2a[k * 32 + j]; }
  for (int i = t; i < 32 * 11; i += 256) { int j = i & 31, k = i >> 5; wpaT[j * 12 + k] = wpa[k * 32 + j]; }
  if (t < 32) {
    float d = (g1b[t] >= 0.f) ? 1.f : -1.f;
    b1bf[t] = d * b1b[t];
    w2aT[t * 44 + 43] = b2a[t];
    wpaT[t * 12 + 11] = bpa[t];
  }
}

// one edge pass (4 edges/thread/iter): dst counts, src out-degrees, per-src ea sums, global ea moments
__global__ __launch_bounds__(256) void k_prep(const int* __restrict__ dst, const int* __restrict__ src,
    const float* __restrict__ ea, int* __restrict__ cnt, int* __restrict__ deg,
    float* __restrict__ sea, float* __restrict__ cmom) {
  float p0 = 0, p1 = 0, p2 = 0, p3 = 0, p4 = 0;
  const int S = gridDim.x * 256;
  for (int g = blockIdx.x * 256 + threadIdx.x; g < EE / 4; g += S) {
    int4 d4 = reinterpret_cast<const int4*>(dst)[g];
    int4 s4 = reinterpret_cast<const int4*>(src)[g];
    float4 e0 = reinterpret_cast<const float4*>(ea)[2 * g];
    float4 e1 = reinterpret_cast<const float4*>(ea)[2 * g + 1];
    atomicAdd(&cnt[d4.x], 1); atomicAdd(&cnt[d4.y], 1); atomicAdd(&cnt[d4.z], 1); atomicAdd(&cnt[d4.w], 1);
    atomicAdd(&deg[s4.x], 1); atomicAdd(&deg[s4.y], 1); atomicAdd(&deg[s4.z], 1); atomicAdd(&deg[s4.w], 1);
    unsafeAtomicAdd(&sea[2 * s4.x], e0.x); unsafeAtomicAdd(&sea[2 * s4.x + 1], e0.y);
    unsafeAtomicAdd(&sea[2 * s4.y], e0.z); unsafeAtomicAdd(&sea[2 * s4.y + 1], e0.w);
    unsafeAtomicAdd(&sea[2 * s4.z], e1.x); unsafeAtomicAdd(&sea[2 * s4.z + 1], e1.y);
    unsafeAtomicAdd(&sea[2 * s4.w], e1.z); unsafeAtomicAdd(&sea[2 * s4.w + 1], e1.w);
    p0 += e0.x * e0.x + e0.z * e0.z + e1.x * e1.x + e1.z * e1.z;
    p1 += e0.x * e0.y + e0.z * e0.w + e1.x * e1.y + e1.z * e1.w;
    p2 += e0.y * e0.y + e0.w * e0.w + e1.y * e1.y + e1.w * e1.w;
    p3 += e0.x + e0.z + e1.x + e1.z;
    p4 += e0.y + e0.w + e1.y + e1.w;
  }
  p0 = wsum(p0); p1 = wsum(p1); p2 = wsum(p2); p3 = wsum(p3); p4 = wsum(p4);
  if ((threadIdx.x & 63) == 0) {
    unsafeAtomicAdd(&cmom[0], p0); unsafeAtomicAdd(&cmom[1], p1); unsafeAtomicAdd(&cmom[2], p2);
    unsafeAtomicAdd(&cmom[3], p3); unsafeAtomicAdd(&cmom[4], p4);
  }
}

__global__ __launch_bounds__(1024) void k_scan(const int* __restrict__ cnt,
                                               int* __restrict__ starts, int* __restrict__ fill) {
  __shared__ int part[1024];
  const int T = 1024, CH = (NN + T - 1) / T;
  int t = threadIdx.x;
  int lo = t * CH, hi = min(lo + CH, NN);
  int s = 0;
  for (int i = lo; i < hi; i++) s += cnt[i];
  part[t] = s; __syncthreads();
  for (int off = 1; off < T; off <<= 1) {
    int v = (t >= off) ? part[t - off] : 0;
    __syncthreads();
    part[t] += v;
    __syncthreads();
  }
  int run = part[t] - s;  // exclusive prefix
  for (int i = lo; i < hi; i++) { starts[i] = run; fill[i] = run; run += cnt[i]; }
  if (t == T - 1) starts[NN] = EE;
}

// scatter packed 16B edge records (src, ea.x, ea.y, 0) into CSR order
__global__ __launch_bounds__(256) void k_scatter(const int* __restrict__ dst, const int* __restrict__ src,
    const float* __restrict__ ea, int* __restrict__ fill, int4* __restrict__ edg) {
  const int S = gridDim.x * 256;
  for (int g = blockIdx.x * 256 + threadIdx.x; g < EE / 4; g += S) {
    int4 d4 = reinterpret_cast<const int4*>(dst)[g];
    int4 s4 = reinterpret_cast<const int4*>(src)[g];
    float4 e0 = reinterpret_cast<const float4*>(ea)[2 * g];
    float4 e1 = reinterpret_cast<const float4*>(ea)[2 * g + 1];
    int p0 = atomicAdd(&fill[d4.x], 1);
    edg[p0] = make_int4(s4.x, __float_as_int(e0.x), __float_as_int(e0.y), 0);
    int p1 = atomicAdd(&fill[d4.y], 1);
    edg[p1] = make_int4(s4.y, __float_as_int(e0.z), __float_as_int(e0.w), 0);
    int p2 = atomicAdd(&fill[d4.z], 1);
    edg[p2] = make_int4(s4.z, __float_as_int(e1.x), __float_as_int(e1.y), 0);
    int p3 = atomicAdd(&fill[d4.w], 1);
    edg[p3] = make_int4(s4.w, __float_as_int(e1.z), __float_as_int(e1.w), 0);
  }
}

// padded node rows: xp[n][0..9]=x cols 0..9, [10]=x col10 (current), [11]=0
__global__ __launch_bounds__(256) void k_xp(const float* __restrict__ x, float* __restrict__ xp) {
  int n = blockIdx.x * 256 + threadIdx.x;
  if (n >= NN) return;
  float v[11];
  #pragma unroll
  for (int k = 0; k < 11; k++) v[k] = x[(size_t)n * 11 + k];
  float4* o = reinterpret_cast<float4*>(xp + (size_t)n * 12);
  o[0] = make_float4(v[0], v[1], v[2], v[3]);
  o[1] = make_float4(v[4], v[5], v[6], v[7]);
  o[2] = make_float4(v[8], v[9], v[10], 0.f);
}

// ---------- per-conv: input moments (node pass, replaces a P1 edge pass) ----------
// mom layout: [0..10]=S_x (deg-weighted), [11..76]=sxx upper-tri(11), [77..98]=sxe
__global__ __launch_bounds__(256) void k_mom(const float* __restrict__ xp, const int* __restrict__ deg,
                                             const float* __restrict__ sea, float* __restrict__ mom) {
  const int n = blockIdx.x * 256 + threadIdx.x;
  const int lane = threadIdx.x & 63;
  float v[11]; float w = 0.f; float sx = 0.f, sy = 0.f;
  #pragma unroll
  for (int k = 0; k < 11; k++) v[k] = 0.f;
  if (n < NN) {
    w = (float)deg[n];
    loadrow(xp, n, v);
    sx = sea[2 * n]; sy = sea[2 * n + 1];
  }
  int ch = 0;
  #pragma unroll
  for (int a = 0; a < 11; a++) {
    float r = wsum(w * v[a]);
    if (lane == 0) unsafeAtomicAdd(&mom[ch], r);
    ch++;
  }
  #pragma unroll
  for (int a = 0; a < 11; a++) {
    #pragma unroll
    for (int b = a; b < 11; b++) {
      float r = wsum(w * v[a] * v[b]);
      if (lane == 0) unsafeAtomicAdd(&mom[ch], r);
      ch++;
    }
  }
  #pragma unroll
  for (int a = 0; a < 11; a++) {
    float rx = wsum(v[a] * sx);
    if (lane == 0) unsafeAtomicAdd(&mom[ch], rx);
    ch++;
    float ry = wsum(v[a] * sy);
    if (lane == 0) unsafeAtomicAdd(&mom[ch], ry);
    ch++;
  }
}

__device__ __forceinline__ float msym(const float* mom, const float* cmom, int k, int l) {
  int a = min(k, l), b = max(k, l);
  if (b < 11) return mom[11 + a * 11 - a * (a - 1) / 2 + (b - a)];
  if (a < 11) return mom[77 + a * 2 + (b - 11)];
  return cmom[(a - 11) + (b - 11)];
}

// layer-1 BN params from moments; emit FOLDED transposed weights w1f[j][0..12]+bias[13]
// plus compact edge-attr weight arrays wexy[0..31]=A*w[11], wexy[32..63]=A*w[12]; zero mom.
__global__ void k_fin1(float* __restrict__ mom, const float* __restrict__ cmom,
    const float* __restrict__ w1a, const float* __restrict__ b1a,
    const float* __restrict__ g1a, const float* __restrict__ be1a,
    float* __restrict__ w1f, float* __restrict__ wexy) {
  int j = threadIdx.x;  // 32 threads
  float w[13], S[13];
  #pragma unroll
  for (int k = 0; k < 13; k++) w[k] = w1a[k * 32 + j];
  #pragma unroll
  for (int k = 0; k < 11; k++) S[k] = mom[k];
  S[11] = cmom[3]; S[12] = cmom[4];
  float lin = 0.f;
  #pragma unroll
  for (int k = 0; k < 13; k++) lin = fmaf(w[k], S[k], lin);
  float quad = 0.f;
  #pragma unroll
  for (int k = 0; k < 13; k++)
    #pragma unroll
    for (int l = 0; l < 13; l++) quad = fmaf(w[k] * w[l], msym(mom, cmom, k, l), quad);
  const float invE = 1.f / EF;
  float b = b1a[j];
  float mean = fmaf(lin, invE, b);
  float ey2 = (quad + 2.f * b * lin) * invE + b * b;
  float var = fmaxf(ey2 - mean * mean, 0.f);
  float A = g1a[j] * rsqrtf(var + 1e-5f);
  float C = be1a[j] - mean * A;
  #pragma unroll
  for (int k = 0; k < 13; k++) w1f[j * 16 + k] = A * w[k];
  w1f[j * 16 + 13] = fmaf(A, b, C);
  w1f[j * 16 + 14] = 0.f; w1f[j * 16 + 15] = 0.f;
  wexy[j] = A * w[11];
  wexy[32 + j] = A * w[12];
  __syncthreads();
  for (int i = j; i < 128; i += 32) mom[i] = 0.f;
}

// P[n][32] = folded layer-1 pre-activation from node features only (edge attrs added per edge)
__global__ __launch_bounds__(256) void k_P(const float* __restrict__ xp, const float* __restrict__ w1f,
                                           float* __restrict__ P) {
  const int n = blockIdx.x * 256 + threadIdx.x;
  if (n >= NN) return;
  float xv[11];
  loadrow(xp, n, xv);
  float4* op = reinterpret_cast<float4*>(P + (size_t)n * 32);
  #pragma unroll
  for (int jj = 0; jj < 8; jj++) {
    float o[4];
    #pragma unroll
    for (int u = 0; u < 4; u++) {
      int j = 4 * jj + u;
      const float* wr = w1f + j * 16;
      float acc = wr[13];
      #pragma unroll
      for (int k = 0; k < 11; k++) acc = fmaf(xv[k], wr[k], acc);
      o[u] = acc;
    }
    op[jj] = make_float4(o[0], o[1], o[2], o[3]);
  }
}

// ---------- fused edge pass: wave-sliced channels ----------
// wave handles channel slice s = wave-id (8 channels); each lane owns one node, iterates all its edges.
// m = relu(P[src] + wex*ea.x + wey*ea.y) computed fully (x4 redundant across slices; ms 4x-counted,
// corrected by 0.25 in k_fin2). z only for the 8 owned channels -> tz (max of d*z), zq (sum z^2).
__global__ __launch_bounds__(256) void k_fusedagg(
    const int* __restrict__ starts, const int4* __restrict__ edg,
    const float* __restrict__ P, const float* __restrict__ wexy,
    const float* __restrict__ w2tf, const float* __restrict__ b1bf,
    float* __restrict__ tzb, float* __restrict__ gms, float* __restrict__ gzq) {
  const int lane = threadIdx.x & 63;
  const int s = __builtin_amdgcn_readfirstlane(threadIdx.x >> 6);  // slice 0..3, SGPR-uniform
  const int n = blockIdx.x * 64 + lane;
  float tz[8], zq[8], ms[32];
  #pragma unroll
  for (int i = 0; i < 8; i++) { tz[i] = -3.0e38f; zq[i] = 0.f; }
  #pragma unroll
  for (int k = 0; k < 32; k++) ms[k] = 0.f;
  int lo = 0, hi = 0;
  if (n < NN) { lo = starts[n]; hi = starts[n + 1]; }
  const float* wsl = w2tf + (size_t)(8 * s) * 32;   // uniform slice base
  for (int sl = lo; sl < hi; ++sl) {
    int4 r = edg[sl];
    float ex = __int_as_float(r.y), ey = __int_as_float(r.z);
    const float4* pr = reinterpret_cast<const float4*>(P + (size_t)r.x * 32);
    float m[32];
    #pragma unroll
    for (int jj = 0; jj < 8; jj++) {
      float4 v = pr[jj];
      m[4*jj+0] = fmaxf(0.f, fmaf(ex, wexy[4*jj+0], fmaf(ey, wexy[32+4*jj+0], v.x)));
      m[4*jj+1] = fmaxf(0.f, fmaf(ex, wexy[4*jj+1], fmaf(ey, wexy[32+4*jj+1], v.y)));
      m[4*jj+2] = fmaxf(0.f, fmaf(ex, wexy[4*jj+2], fmaf(ey, wexy[32+4*jj+2], v.z)));
      m[4*jj+3] = fmaxf(0.f, fmaf(ex, wexy[4*jj+3], fmaf(ey, wexy[32+4*jj+3], v.w)));
    }
    #pragma unroll
    for (int k = 0; k < 32; k++) ms[k] += m[k];
    #pragma unroll
    for (int i = 0; i < 8; i++) {
      const float* wr = wsl + i * 32;                // uniform -> s_loads
      float z0 = b1bf[8 * s + i], z1 = 0.f;
      #pragma unroll
      for (int k = 0; k < 32; k += 2) { z0 = fmaf(m[k], wr[k], z0); z1 = fmaf(m[k+1], wr[k+1], z1); }
      float z = z0 + z1;
      tz[i] = fmaxf(tz[i], z);
      zq[i] = fmaf(z, z, zq[i]);
    }
  }
  if (n < NN) {
    float4* ot = reinterpret_cast<float4*>(tzb + (size_t)n * 32 + 8 * s);
    ot[0] = make_float4(tz[0], tz[1], tz[2], tz[3]);
    ot[1] = make_float4(tz[4], tz[5], tz[6], tz[7]);
  }
  // stats: ms over all 32 channels (x4-counted globally), zq for the 8 owned channels
  #pragma unroll
  for (int k = 0; k < 32; k++) {
    float a = wsum(ms[k]);
    if (lane == 0) unsafeAtomicAdd(&gms[k], a);
  }
  #pragma unroll
  for (int i = 0; i < 8; i++) {
    float b = wsum(zq[i]);
    if (lane == 0) unsafeAtomicAdd(&gzq[8 * s + i], b);
  }
}

// layer-2 BN: zs_j = w1b[:,j]·(ms*0.25) + E*b1b_j; A2d = A2*sign(g1b); zero ms/zq
__global__ void k_fin2(float* __restrict__ ms, float* __restrict__ zq,
    const float* __restrict__ w1b, const float* __restrict__ b1b,
    const float* __restrict__ g1b, const float* __restrict__ be1b,
    float* __restrict__ A2d, float* __restrict__ C2) {
  __shared__ float sm[32];
  int j = threadIdx.x;  // 32 threads
  sm[j] = ms[j] * 0.25f;   // ms was accumulated by all 4 slices
  __syncthreads();
  float zs = EF * b1b[j];
  #pragma unroll
  for (int k = 0; k < 32; k++) zs = fmaf(w1b[k * 32 + j], sm[k], zs);
  const float invE = 1.f / EF;
  float mu = zs * invE;
  float var = fmaxf(zq[j] * invE - mu * mu, 0.f);
  float A = g1b[j] * rsqrtf(var + 1e-5f);
  float C = be1b[j] - mu * A;
  float d = (g1b[j] >= 0.f) ? 1.f : -1.f;
  A2d[j] = A * d; C2[j] = C;
  ms[j] = 0.f; zq[j] = 0.f;
}

// BN finalize: a = g*rsqrt(var+eps), c = be - mu*a; zero sums for reuse
__global__ void k_finalize(float* __restrict__ sum, float* __restrict__ ssq,
                           const float* __restrict__ g, const float* __restrict__ be,
                           float inv_n, int ncols, float* __restrict__ a, float* __restrict__ c) {
  int j = threadIdx.x;
  if (j < ncols) {
    float mu = sum[j] * inv_n;
    float var = fmaxf(ssq[j] * inv_n - mu * mu, 0.f);
    float s = rsqrtf(var + 1e-5f) * g[j];
    a[j] = s; c[j] = be[j] - mu * s;
    sum[j] = 0.f; ssq[j] = 0.f;
  }
}

// ---------- agg finalize + h_pre = [x, agg] @ w2a + b2a (+stats) ----------

__global__ __launch_bounds__(256) void k_hpre2(const float* __restrict__ xp,
    const float* __restrict__ tzb, const int* __restrict__ starts,
    const float* __restrict__ A2d, const float* __restrict__ C2, const float* __restrict__ w2aT,
    float* __restrict__ hpre, float* __restrict__ gsum, float* __restrict__ gssq) {
  __shared__ float red[256];
  const int n = blockIdx.x * 256 + threadIdx.x;
  float h[32], hh[32];
  #pragma unroll
  for (int j = 0; j < 32; j++) h[j] = 0.f;
  if (n < NN) {
    float xv[11];
    loadrow(xp, n, xv);
    const int dg = starts[n + 1] - starts[n];
    float av[32];
    if (dg > 0) {
      const float4* tp = reinterpret_cast<const float4*>(tzb + (size_t)n * 32);
      #pragma unroll
      for (int j = 0; j < 8; j++) {
        float4 v = tp[j];
        av[4 * j]     = fmaxf(0.f, fmaf(A2d[4 * j],     v.x, C2[4 * j]));
        av[4 * j + 1] = fmaxf(0.f, fmaf(A2d[4 * j + 1], v.y, C2[4 * j + 1]));
        av[4 * j + 2] = fmaxf(0.f, fmaf(A2d[4 * j + 2], v.z, C2[4 * j + 2]));
        av[4 * j + 3] = fmaxf(0.f, fmaf(A2d[4 * j + 3], v.w, C2[4 * j + 3]));
      }
    } else {
      #pragma unroll
      for (int j = 0; j < 32; j++) av[j] = 0.f;
    }
    #pragma unroll
    for (int j = 0; j < 32; j++) {
      const float* wr = w2aT + j * 44;
      float acc = wr[43];
      #pragma unroll
      for (int k = 0; k < 11; k++) acc = fmaf(xv[k], wr[k], acc);
      #pragma unroll
      for (int k = 0; k < 32; k++) acc = fmaf(av[k], wr[11 + k], acc);
      h[j] = acc;
    }
    float4* hp = reinterpret_cast<float4*>(hpre + (size_t)n * 32);
    #pragma unroll
    for (int j = 0; j < 8; j++)
      hp[j] = make_float4(h[4 * j], h[4 * j + 1], h[4 * j + 2], h[4 * j + 3]);
  }
  #pragma unroll
  for (int j = 0; j < 32; j++) hh[j] = h[j] * h[j];
  reduce64(h, hh, red, gsum, gssq);
}

// comb = relu(relu(bn(h_pre)) @ w2b + b2b) -> xp col 10
__global__ __launch_bounds__(256) void k_comb(const float* __restrict__ hpre,
    const float* __restrict__ a3, const float* __restrict__ c3,
    const float* __restrict__ w2b, const float* __restrict__ b2b, float* __restrict__ xp) {
  const int n = blockIdx.x * 256 + threadIdx.x;
  if (n >= NN) return;
  const float4* hp = reinterpret_cast<const float4*>(hpre + (size_t)n * 32);
  float acc = b2b[0];
  #pragma unroll
  for (int j = 0; j < 8; j++) {
    float4 v = hp[j];
    acc += fmaxf(0.f, fmaf(v.x, a3[4 * j],     c3[4 * j]))     * w2b[4 * j];
    acc += fmaxf(0.f, fmaf(v.y, a3[4 * j + 1], c3[4 * j + 1])) * w2b[4 * j + 1];
    acc += fmaxf(0.f, fmaf(v.z, a3[4 * j + 2], c3[4 * j + 2])) * w2b[4 * j + 2];
    acc += fmaxf(0.f, fmaf(v.w, a3[4 * j + 3], c3[4 * j + 3])) * w2b[4 * j + 3];
  }
  xp[(size_t)n * 12 + 10] = fmaxf(acc, 0.f);
}

// ---------- power MLP ----------

// yp = x @ wpa + bpa : store to ybuf + stats
__global__ __launch_bounds__(256) void k_p5(const float* __restrict__ xp, const float* __restrict__ wpaT,
                                            float* __restrict__ ybuf,
                                            float* __restrict__ gsum, float* __restrict__ gssq) {
  __shared__ float red[256];
  const int n = blockIdx.x * 256 + threadIdx.x;
  float y[32], yy[32];
  #pragma unroll
  for (int j = 0; j < 32; j++) y[j] = 0.f;
  if (n < NN) {
    float xv[11];
    loadrow(xp, n, xv);
    #pragma unroll
    for (int j = 0; j < 32; j++) {
      const float* wr = wpaT + j * 12;
      float acc = wr[11];
      #pragma unroll
      for (int k = 0; k < 11; k++) acc = fmaf(xv[k], wr[k], acc);
      y[j] = acc;
    }
    float4* yp = reinterpret_cast<float4*>(ybuf + (size_t)n * 32);
    #pragma unroll
    for (int j = 0; j < 8; j++)
      yp[j] = make_float4(y[4 * j], y[4 * j + 1], y[4 * j + 2], y[4 * j + 3]);
  }
  #pragma unroll
  for (int j = 0; j < 32; j++) yy[j] = y[j] * y[j];
  reduce64(y, yy, red, gsum, gssq);
}

// yq = relu(bn(yp)) @ wpb + bpb : store + scalar stats (reads stored yp)
__global__ __launch_bounds__(256) void k_p6(const float* __restrict__ ybuf,
    const float* __restrict__ a4, const float* __restrict__ c4,
    const float* __restrict__ wpb, const float* __restrict__ bpb,
    float* __restrict__ yq, float* __restrict__ gsum, float* __restrict__ gssq) {
  __shared__ float red[8];
  const int n = blockIdx.x * 256 + threadIdx.x;
  float sum = 0.f, ssq = 0.f;
  if (n < NN) {
    const float4* yp = reinterpret_cast<const float4*>(ybuf + (size_t)n * 32);
    float q = bpb[0];
    #pragma unroll
    for (int j = 0; j < 8; j++) {
      float4 v = yp[j];
      q = fmaf(fmaxf(0.f, fmaf(v.x, a4[4 * j],     c4[4 * j])),     wpb[4 * j],     q);
      q = fmaf(fmaxf(0.f, fmaf(v.y, a4[4 * j + 1], c4[4 * j + 1])), wpb[4 * j + 1], q);
      q = fmaf(fmaxf(0.f, fmaf(v.z, a4[4 * j + 2], c4[4 * j + 2])), wpb[4 * j + 2], q);
      q = fmaf(fmaxf(0.f, fmaf(v.w, a4[4 * j + 3], c4[4 * j + 3])), wpb[4 * j + 3], q);
    }
    yq[n] = q;
    sum = q; ssq = q * q;
  }
  float s = wsum(sum), qq = wsum(ssq);
  const int wid = threadIdx.x >> 6, lane = threadIdx.x & 63;
  if (lane == 0) { red[wid] = s; red[4 + wid] = qq; }
  __syncthreads();
  if (threadIdx.x == 0) {
    unsafeAtomicAdd(&gsum[0], red[0] + red[1] + red[2] + red[3]);
    unsafeAtomicAdd(&gssq[0], red[4] + red[5] + red[6] + red[7]);
  }
}

__global__ __launch_bounds__(256) void k_p7(const float* __restrict__ yq,
    const float* __restrict__ a5, const float* __restrict__ c5, float* __restrict__ out) {
  int n = blockIdx.x * 256 + threadIdx.x;
  if (n < NN) out[n] = fmaxf(0.f, fmaf(yq[n], a5[0], c5[0]));
}

// ---------- host launch ----------

extern "C" void kernel_launch(void* const* d_in, const int* in_sizes, int n_in,
                              void* d_out, int out_size, void* d_ws, size_t ws_size,
                              hipStream_t stream) {
  const float* x    = (const float*)d_in[0];
  const float* ea   = (const float*)d_in[1];
  const int*   ei   = (const int*)d_in[2];
  const int*   srcp = ei;
  const int*   dstp = ei + EE;
  const float* w1a = (const float*)d_in[3],  *b1a = (const float*)d_in[4];
  const float* g1a = (const float*)d_in[5],  *be1a = (const float*)d_in[6];
  const float* w1b = (const float*)d_in[7],  *b1b = (const float*)d_in[8];
  const float* g1b = (const float*)d_in[9],  *be1b = (const float*)d_in[10];
  const float* w2a = (const float*)d_in[11], *b2a = (const float*)d_in[12];
  const float* g2a = (const float*)d_in[13], *be2a = (const float*)d_in[14];
  const float* w2b = (const float*)d_in[15], *b2b = (const float*)d_in[16];
  const float* wpa = (const float*)d_in[17], *bpa = (const float*)d_in[18];
  const float* gpa = (const float*)d_in[19], *bepa = (const float*)d_in[20];
  const float* wpb = (const float*)d_in[21], *bpb = (const float*)d_in[22];
  const float* gpb = (const float*)d_in[23], *bepb = (const float*)d_in[24];

  size_t off = 0;
  char* base = (char*)d_ws;
  auto alloc = [&](size_t bytes) -> void* {
    void* p = base + off;
    off += (bytes + 255) & ~(size_t)255;
    return p;
  };
  float* stats = (float*)alloc(2048);
  float* coef  = (float*)alloc(2048);
  float* mom   = (float*)alloc(512);
  float* cmom  = (float*)alloc(256);
  float* w1f   = (float*)alloc(16 * 32 * 4);
  float* wexy  = (float*)alloc(64 * 4);
  float* w2tf  = (float*)alloc(32 * 32 * 4);
  float* b1bf  = (float*)alloc(256);
  float* w2aT  = (float*)alloc(32 * 44 * 4);
  float* wpaT  = (float*)alloc(32 * 12 * 4);
  int*   cnt    = (int*)alloc(NN * 4);
  int*   deg    = (int*)alloc(NN * 4);
  float* sea    = (float*)alloc((size_t)NN * 2 * 4);
  int*   starts = (int*)alloc((NN + 1) * 4);
  int*   fill   = (int*)alloc(NN * 4);
  int4*  edg    = (int4*)alloc((size_t)EE * 16);
  float* xp     = (float*)alloc((size_t)NN * 12 * 4);
  float* P      = (float*)alloc((size_t)NN * 32 * 4);
  float* tzb    = (float*)alloc((size_t)NN * 32 * 4);
  float* hpre   = (float*)alloc((size_t)NN * 32 * 4);
  float* yq     = (float*)alloc(NN * 4);

  float *MS2  = stats,       *ZQ2  = stats + 32;
  float *SUM3 = stats + 64,  *SSQ3 = stats + 96;
  float *SUM4 = stats + 128, *SSQ4 = stats + 160;
  float *SUM5 = stats + 192, *SSQ5 = stats + 224;
  float *A2d = coef,       *C2 = coef + 32;
  float *A3  = coef + 64,  *C3 = coef + 96;
  float *A4  = coef + 128, *C4 = coef + 160;
  float *A5  = coef + 192, *C5 = coef + 224;

  hipMemsetAsync(stats, 0, 2048, stream);
  hipMemsetAsync(mom, 0, 512 + 256, stream);   // mom + cmom
  hipMemsetAsync(cnt, 0, NN * 4, stream);
  hipMemsetAsync(deg, 0, NN * 4, stream);
  hipMemsetAsync(sea, 0, (size_t)NN * 2 * 4, stream);

  const int GN = (NN + 255) / 256;          // 391
  const int GW = (NN + 63) / 64;            // 1563 blocks: 64 nodes x 4 channel-slice waves
  const int GE4 = (EE / 4 + 255) / 256;     // 3125

  k_wprep  <<<1, 256, 0, stream>>>(w1b, b1b, g1b, w2a, b2a, wpa, bpa, w2tf, b1bf, w2aT, wpaT);
  k_prep   <<<GE4, 256, 0, stream>>>(dstp, srcp, ea, cnt, deg, sea, cmom);
  k_scan   <<<1, 1024, 0, stream>>>(cnt, starts, fill);
  k_scatter<<<GE4, 256, 0, stream>>>(dstp, srcp, ea, fill, edg);
  k_xp     <<<GN, 256, 0, stream>>>(x, xp);

  const float invN = 1.f / (float)NN;
  for (int c = 0; c < 3; c++) {
    k_mom     <<<GN, 256, 0, stream>>>(xp, deg, sea, mom);
    k_fin1    <<<1, 32, 0, stream>>>(mom, cmom, w1a, b1a, g1a, be1a, w1f, wexy);
    k_P       <<<GN, 256, 0, stream>>>(xp, w1f, P);
    k_fusedagg<<<GW, 256, 0, stream>>>(starts, edg, P, wexy, w2tf, b1bf, tzb, MS2, ZQ2);
    k_fin2    <<<1, 32, 0, stream>>>(MS2, ZQ2, w1b, b1b, g1b, be1b, A2d, C2);
    k_hpre2   <<<GN, 256, 0, stream>>>(xp, tzb, starts, A2d, C2, w2aT, hpre, SUM3, SSQ3);
    k_finalize<<<1, 32, 0, stream>>>(SUM3, SSQ3, g2a, be2a, invN, 32, A3, C3);
    k_comb    <<<GN, 256, 0, stream>>>(hpre, A3, C3, w2b, b2b, xp);
  }

  k_p5      <<<GN, 256, 0, stream>>>(xp, wpaT, hpre, SUM4, SSQ4);
  k_finalize<<<1, 32, 0, stream>>>(SUM4, SSQ4, gpa, bepa, invN, 32, A4, C4);
  k_p6      <<<GN, 256, 0, stream>>>(hpre, A4, C4, wpb, bpb, yq, SUM5, SSQ5);
  k_finalize<<<1, 32, 0, stream>>>(SUM5, SSQ5, gpb, bepb, invN, 1, A5, C5);
  k_p7      <<<GN, 256, 0, stream>>>(yq, A5, C5, (float*)d_out);
}

// Round 5
// 7947.596 us; speedup vs baseline: 1.5428x; 1.2041x over previous
//
#include <hip/hip_runtime.h>
#include <hip/hip_bf16.h>
#include <cstddef>

#define NN 100000
#define EE 3200000
static const float EF = 3200000.0f;

// ---------- helpers ----------

__device__ __forceinline__ float wsum(float v) {
  #pragma unroll
  for (int off = 32; off > 0; off >>= 1) v += __shfl_down(v, off, 64);
  return v;  // lane 0 holds wave total
}

// block-level reduce of 32 sums + 32 sumsq -> global atomics. red = shared float[256].
__device__ __forceinline__ void reduce64(float sum[32], float ssq[32], float* red,
                                         float* __restrict__ gsum, float* __restrict__ gssq) {
  const int wid = threadIdx.x >> 6, lane = threadIdx.x & 63;
  #pragma unroll
  for (int j = 0; j < 32; j++) {
    float a = wsum(sum[j]);
    float b = wsum(ssq[j]);
    if (lane == 0) { red[wid * 64 + j] = a; red[wid * 64 + 32 + j] = b; }
  }
  __syncthreads();
  if (threadIdx.x < 64) {
    float t = red[threadIdx.x] + red[64 + threadIdx.x] + red[128 + threadIdx.x] + red[192 + threadIdx.x];
    if (threadIdx.x < 32) unsafeAtomicAdd(&gsum[threadIdx.x], t);
    else                  unsafeAtomicAdd(&gssq[threadIdx.x - 32], t);
  }
}

__device__ __forceinline__ void loadrow(const float* __restrict__ xp, int s, float in[13]) {
  const float4* xr = reinterpret_cast<const float4*>(xp + (size_t)s * 12);
  float4 r0 = xr[0], r1 = xr[1], r2 = xr[2];
  in[0]=r0.x; in[1]=r0.y; in[2]=r0.z; in[3]=r0.w; in[4]=r1.x; in[5]=r1.y; in[6]=r1.z; in[7]=r1.w;
  in[8]=r2.x; in[9]=r2.y; in[10]=r2.z;
}

// ---------- setup kernels ----------

// w2tf[j][k] = d_j * w1b[k][j] (d_j = sign(g1b_j)); b1bf[j] = d_j*b1b[j];
// w2aT[j][0..42]+bias at 43; wpaT[j][0..10]+bias at 11
__global__ __launch_bounds__(256) void k_wprep(const float* __restrict__ w1b,
    const float* __restrict__ b1b, const float* __restrict__ g1b,
    const float* __restrict__ w2a, const float* __restrict__ b2a,
    const float* __restrict__ wpa, const float* __restrict__ bpa,
    float* __restrict__ w2tf, float* __restrict__ b1bf,
    float* __restrict__ w2aT, float* __restrict__ wpaT) {
  int t = threadIdx.x;
  for (int i = t; i < 1024; i += 256) {
    int j = i >> 5, k = i & 31;
    float d = (g1b[j] >= 0.f) ? 1.f : -1.f;
    w2tf[j * 32 + k] = d * w1b[k * 32 + j];
  }
  for (int i = t; i < 32 * 43; i += 256) { int j = i & 31, k = i >> 5; w2aT[j * 44 + k] = w2a[k * 32 + j]; }
  for (int i = t; i < 32 * 11; i += 256) { int j = i & 31, k = i >> 5; wpaT[j * 12 + k] = wpa[k * 32 + j]; }
  if (t < 32) {
    float d = (g1b[t] >= 0.f) ? 1.f : -1.f;
    b1bf[t] = d * b1b[t];
    w2aT[t * 44 + 43] = b2a[t];
    wpaT[t * 12 + 11] = bpa[t];
  }
}

// one edge pass (4 edges/thread/iter): dst counts, src out-degrees, per-src ea sums, global ea moments
__global__ __launch_bounds__(256) void k_prep(const int* __restrict__ dst, const int* __restrict__ src,
    const float* __restrict__ ea, int* __restrict__ cnt, int* __restrict__ deg,
    float* __restrict__ sea, float* __restrict__ cmom) {
  float p0 = 0, p1 = 0, p2 = 0, p3 = 0, p4 = 0;
  const int S = gridDim.x * 256;
  for (int g = blockIdx.x * 256 + threadIdx.x; g < EE / 4; g += S) {
    int4 d4 = reinterpret_cast<const int4*>(dst)[g];
    int4 s4 = reinterpret_cast<const int4*>(src)[g];
    float4 e0 = reinterpret_cast<const float4*>(ea)[2 * g];
    float4 e1 = reinterpret_cast<const float4*>(ea)[2 * g + 1];
    atomicAdd(&cnt[d4.x], 1); atomicAdd(&cnt[d4.y], 1); atomicAdd(&cnt[d4.z], 1); atomicAdd(&cnt[d4.w], 1);
    atomicAdd(&deg[s4.x], 1); atomicAdd(&deg[s4.y], 1); atomicAdd(&deg[s4.z], 1); atomicAdd(&deg[s4.w], 1);
    unsafeAtomicAdd(&sea[2 * s4.x], e0.x); unsafeAtomicAdd(&sea[2 * s4.x + 1], e0.y);
    unsafeAtomicAdd(&sea[2 * s4.y], e0.z); unsafeAtomicAdd(&sea[2 * s4.y + 1], e0.w);
    unsafeAtomicAdd(&sea[2 * s4.z], e1.x); unsafeAtomicAdd(&sea[2 * s4.z + 1], e1.y);
    unsafeAtomicAdd(&sea[2 * s4.w], e1.z); unsafeAtomicAdd(&sea[2 * s4.w + 1], e1.w);
    p0 += e0.x * e0.x + e0.z * e0.z + e1.x * e1.x + e1.z * e1.z;
    p1 += e0.x * e0.y + e0.z * e0.w + e1.x * e1.y + e1.z * e1.w;
    p2 += e0.y * e0.y + e0.w * e0.w + e1.y * e1.y + e1.w * e1.w;
    p3 += e0.x + e0.z + e1.x + e1.z;
    p4 += e0.y + e0.w + e1.y + e1.w;
  }
  p0 = wsum(p0); p1 = wsum(p1); p2 = wsum(p2); p3 = wsum(p3); p4 = wsum(p4);
  if ((threadIdx.x & 63) == 0) {
    unsafeAtomicAdd(&cmom[0], p0); unsafeAtomicAdd(&cmom[1], p1); unsafeAtomicAdd(&cmom[2], p2);
    unsafeAtomicAdd(&cmom[3], p3); unsafeAtomicAdd(&cmom[4], p4);
  }
}

__global__ __launch_bounds__(1024) void k_scan(const int* __restrict__ cnt,
                                               int* __restrict__ starts, int* __restrict__ fill) {
  __shared__ int part[1024];
  const int T = 1024, CH = (NN + T - 1) / T;
  int t = threadIdx.x;
  int lo = t * CH, hi = min(lo + CH, NN);
  int s = 0;
  for (int i = lo; i < hi; i++) s += cnt[i];
  part[t] = s; __syncthreads();
  for (int off = 1; off < T; off <<= 1) {
    int v = (t >= off) ? part[t - off] : 0;
    __syncthreads();
    part[t] += v;
    __syncthreads();
  }
  int run = part[t] - s;  // exclusive prefix
  for (int i = lo; i < hi; i++) { starts[i] = run; fill[i] = run; run += cnt[i]; }
  if (t == T - 1) starts[NN] = EE;
}

// scatter packed 16B edge records (src, ea.x, ea.y, 0) into CSR order
__global__ __launch_bounds__(256) void k_scatter(const int* __restrict__ dst, const int* __restrict__ src,
    const float* __restrict__ ea, int* __restrict__ fill, int4* __restrict__ edg) {
  const int S = gridDim.x * 256;
  for (int g = blockIdx.x * 256 + threadIdx.x; g < EE / 4; g += S) {
    int4 d4 = reinterpret_cast<const int4*>(dst)[g];
    int4 s4 = reinterpret_cast<const int4*>(src)[g];
    float4 e0 = reinterpret_cast<const float4*>(ea)[2 * g];
    float4 e1 = reinterpret_cast<const float4*>(ea)[2 * g + 1];
    int p0 = atomicAdd(&fill[d4.x], 1);
    edg[p0] = make_int4(s4.x, __float_as_int(e0.x), __float_as_int(e0.y), 0);
    int p1 = atomicAdd(&fill[d4.y], 1);
    edg[p1] = make_int4(s4.y, __float_as_int(e0.z), __float_as_int(e0.w), 0);
    int p2 = atomicAdd(&fill[d4.z], 1);
    edg[p2] = make_int4(s4.z, __float_as_int(e1.x), __float_as_int(e1.y), 0);
    int p3 = atomicAdd(&fill[d4.w], 1);
    edg[p3] = make_int4(s4.w, __float_as_int(e1.z), __float_as_int(e1.w), 0);
  }
}

// padded node rows: xp[n][0..9]=x cols 0..9, [10]=x col10 (current), [11]=0
__global__ __launch_bounds__(256) void k_xp(const float* __restrict__ x, float* __restrict__ xp) {
  int n = blockIdx.x * 256 + threadIdx.x;
  if (n >= NN) return;
  float v[11];
  #pragma unroll
  for (int k = 0; k < 11; k++) v[k] = x[(size_t)n * 11 + k];
  float4* o = reinterpret_cast<float4*>(xp + (size_t)n * 12);
  o[0] = make_float4(v[0], v[1], v[2], v[3]);
  o[1] = make_float4(v[4], v[5], v[6], v[7]);
  o[2] = make_float4(v[8], v[9], v[10], 0.f);
}

// ---------- per-conv: input moments (node pass, replaces a P1 edge pass) ----------
// mom layout: [0..10]=S_x (deg-weighted), [11..76]=sxx upper-tri(11), [77..98]=sxe
__global__ __launch_bounds__(256) void k_mom(const float* __restrict__ xp, const int* __restrict__ deg,
                                             const float* __restrict__ sea, float* __restrict__ mom) {
  const int n = blockIdx.x * 256 + threadIdx.x;
  const int lane = threadIdx.x & 63;
  float v[11]; float w = 0.f; float sx = 0.f, sy = 0.f;
  #pragma unroll
  for (int k = 0; k < 11; k++) v[k] = 0.f;
  if (n < NN) {
    w = (float)deg[n];
    loadrow(xp, n, v);
    sx = sea[2 * n]; sy = sea[2 * n + 1];
  }
  int ch = 0;
  #pragma unroll
  for (int a = 0; a < 11; a++) {
    float r = wsum(w * v[a]);
    if (lane == 0) unsafeAtomicAdd(&mom[ch], r);
    ch++;
  }
  #pragma unroll
  for (int a = 0; a < 11; a++) {
    #pragma unroll
    for (int b = a; b < 11; b++) {
      float r = wsum(w * v[a] * v[b]);
      if (lane == 0) unsafeAtomicAdd(&mom[ch], r);
      ch++;
    }
  }
  #pragma unroll
  for (int a = 0; a < 11; a++) {
    float rx = wsum(v[a] * sx);
    if (lane == 0) unsafeAtomicAdd(&mom[ch], rx);
    ch++;
    float ry = wsum(v[a] * sy);
    if (lane == 0) unsafeAtomicAdd(&mom[ch], ry);
    ch++;
  }
}

__device__ __forceinline__ float msym(const float* mom, const float* cmom, int k, int l) {
  int a = min(k, l), b = max(k, l);
  if (b < 11) return mom[11 + a * 11 - a * (a - 1) / 2 + (b - a)];
  if (a < 11) return mom[77 + a * 2 + (b - 11)];
  return cmom[(a - 11) + (b - 11)];
}

// layer-1 BN params from moments; emit FOLDED transposed weights w1f[j][0..12]+bias[13]
// plus compact edge-attr weight arrays wexy[0..31]=A*w[11], wexy[32..63]=A*w[12]; zero mom.
__global__ void k_fin1(float* __restrict__ mom, const float* __restrict__ cmom,
    const float* __restrict__ w1a, const float* __restrict__ b1a,
    const float* __restrict__ g1a, const float* __restrict__ be1a,
    float* __restrict__ w1f, float* __restrict__ wexy) {
  int j = threadIdx.x;  // 32 threads
  float w[13], S[13];
  #pragma unroll
  for (int k = 0; k < 13; k++) w[k] = w1a[k * 32 + j];
  #pragma unroll
  for (int k = 0; k < 11; k++) S[k] = mom[k];
  S[11] = cmom[3]; S[12] = cmom[4];
  float lin = 0.f;
  #pragma unroll
  for (int k = 0; k < 13; k++) lin = fmaf(w[k], S[k], lin);
  float quad = 0.f;
  #pragma unroll
  for (int k = 0; k < 13; k++)
    #pragma unroll
    for (int l = 0; l < 13; l++) quad = fmaf(w[k] * w[l], msym(mom, cmom, k, l), quad);
  const float invE = 1.f / EF;
  float b = b1a[j];
  float mean = fmaf(lin, invE, b);
  float ey2 = (quad + 2.f * b * lin) * invE + b * b;
  float var = fmaxf(ey2 - mean * mean, 0.f);
  float A = g1a[j] * rsqrtf(var + 1e-5f);
  float C = be1a[j] - mean * A;
  #pragma unroll
  for (int k = 0; k < 13; k++) w1f[j * 16 + k] = A * w[k];
  w1f[j * 16 + 13] = fmaf(A, b, C);
  w1f[j * 16 + 14] = 0.f; w1f[j * 16 + 15] = 0.f;
  wexy[j] = A * w[11];
  wexy[32 + j] = A * w[12];
  __syncthreads();
  for (int i = j; i < 128; i += 32) mom[i] = 0.f;
}

// P[n][32] = folded layer-1 pre-activation from node features only (edge attrs added per edge)
__global__ __launch_bounds__(256) void k_P(const float* __restrict__ xp, const float* __restrict__ w1f,
                                           float* __restrict__ P) {
  const int n = blockIdx.x * 256 + threadIdx.x;
  if (n >= NN) return;
  float xv[11];
  loadrow(xp, n, xv);
  float4* op = reinterpret_cast<float4*>(P + (size_t)n * 32);
  #pragma unroll
  for (int jj = 0; jj < 8; jj++) {
    float o[4];
    #pragma unroll
    for (int u = 0; u < 4; u++) {
      int j = 4 * jj + u;
      const float* wr = w1f + j * 16;
      float acc = wr[13];
      #pragma unroll
      for (int k = 0; k < 11; k++) acc = fmaf(xv[k], wr[k], acc);
      o[u] = acc;
    }
    op[jj] = make_float4(o[0], o[1], o[2], o[3]);
  }
}

// ---------- fused edge pass: wave-sliced channels, 2 lanes/node, software-pipelined ----------
// wave s handles channels [8s,8s+8); lanes 0-31 = nodes (parity 0), lanes 32-63 = same nodes (parity 1).
// Each lane walks its node's CSR stream with stride 2, prefetching the next edge record + P row
// while computing the current one. ms8 = per-slice Σm (each channel counted exactly once globally).
__global__ __launch_bounds__(256, 4) void k_fusedagg(
    const int* __restrict__ starts, const int4* __restrict__ edg,
    const float* __restrict__ P, const float* __restrict__ wexy,
    const float* __restrict__ w2tf, const float* __restrict__ b1bf,
    float* __restrict__ tzb, float* __restrict__ gms, float* __restrict__ gzq) {
  const int lane = threadIdx.x & 63;
  const int s = __builtin_amdgcn_readfirstlane(threadIdx.x >> 6);  // slice 0..3, SGPR-uniform
  const int nl = lane & 31, q = lane >> 5;
  const int n = blockIdx.x * 32 + nl;
  float tz[8], zq[8], ms8[8];
  #pragma unroll
  for (int i = 0; i < 8; i++) { tz[i] = -3.0e38f; zq[i] = 0.f; ms8[i] = 0.f; }
  int lo = 0, hi = 0;
  if (n < NN) { lo = starts[n]; hi = starts[n + 1]; }
  const float* wsl = w2tf + (size_t)(8 * s) * 32;   // uniform slice base
  float bz[8];
  #pragma unroll
  for (int i = 0; i < 8; i++) bz[i] = b1bf[8 * s + i];

  int sl = lo + q;
  int4 r = make_int4(0, 0, 0, 0);
  float4 pc0, pc1, pc2, pc3, pc4, pc5, pc6, pc7;
  if (sl < hi) {
    r = edg[sl];
    const float4* pr = reinterpret_cast<const float4*>(P + (size_t)r.x * 32);
    pc0 = pr[0]; pc1 = pr[1]; pc2 = pr[2]; pc3 = pr[3];
    pc4 = pr[4]; pc5 = pr[5]; pc6 = pr[6]; pc7 = pr[7];
  }
  while (sl < hi) {
    const int sln = sl + 2;
    int4 rn = r;
    float4 pn0 = pc0, pn1 = pc1, pn2 = pc2, pn3 = pc3, pn4 = pc4, pn5 = pc5, pn6 = pc6, pn7 = pc7;
    if (sln < hi) {   // prefetch next edge while computing current
      rn = edg[sln];
      const float4* pr = reinterpret_cast<const float4*>(P + (size_t)rn.x * 32);
      pn0 = pr[0]; pn1 = pr[1]; pn2 = pr[2]; pn3 = pr[3];
      pn4 = pr[4]; pn5 = pr[5]; pn6 = pr[6]; pn7 = pr[7];
    }
    const float ex = __int_as_float(r.y), ey = __int_as_float(r.z);
    float z[8];
    #pragma unroll
    for (int i = 0; i < 8; i++) z[i] = bz[i];
    #pragma unroll
    for (int jj = 0; jj < 8; jj++) {
      float4 v;
      switch (jj) {
        case 0: v = pc0; break; case 1: v = pc1; break; case 2: v = pc2; break; case 3: v = pc3; break;
        case 4: v = pc4; break; case 5: v = pc5; break; case 6: v = pc6; break; default: v = pc7; break;
      }
      float m0 = fmaxf(0.f, fmaf(ex, wexy[4*jj+0], fmaf(ey, wexy[32+4*jj+0], v.x)));
      float m1 = fmaxf(0.f, fmaf(ex, wexy[4*jj+1], fmaf(ey, wexy[32+4*jj+1], v.y)));
      float m2 = fmaxf(0.f, fmaf(ex, wexy[4*jj+2], fmaf(ey, wexy[32+4*jj+2], v.z)));
      float m3 = fmaxf(0.f, fmaf(ex, wexy[4*jj+3], fmaf(ey, wexy[32+4*jj+3], v.w)));
      if ((jj >> 1) == s) {   // uniform branch: accumulate Σm for owned channels only
        const int b = 4 * (jj & 1);
        ms8[b + 0] += m0; ms8[b + 1] += m1; ms8[b + 2] += m2; ms8[b + 3] += m3;
      }
      #pragma unroll
      for (int i = 0; i < 8; i++) {
        z[i] = fmaf(m0, wsl[i * 32 + 4*jj + 0], z[i]);
        z[i] = fmaf(m1, wsl[i * 32 + 4*jj + 1], z[i]);
        z[i] = fmaf(m2, wsl[i * 32 + 4*jj + 2], z[i]);
        z[i] = fmaf(m3, wsl[i * 32 + 4*jj + 3], z[i]);
      }
    }
    #pragma unroll
    for (int i = 0; i < 8; i++) {
      tz[i] = fmaxf(tz[i], z[i]);
      zq[i] = fmaf(z[i], z[i], zq[i]);
    }
    sl = sln;
    r = rn;
    pc0 = pn0; pc1 = pn1; pc2 = pn2; pc3 = pn3; pc4 = pn4; pc5 = pn5; pc6 = pn6; pc7 = pn7;
  }
  // combine parity pair (lane <-> lane^32)
  #pragma unroll
  for (int i = 0; i < 8; i++) tz[i] = fmaxf(tz[i], __shfl_xor(tz[i], 32, 64));
  if (q == 0 && n < NN) {
    float4* ot = reinterpret_cast<float4*>(tzb + (size_t)n * 32 + 8 * s);
    ot[0] = make_float4(tz[0], tz[1], tz[2], tz[3]);
    ot[1] = make_float4(tz[4], tz[5], tz[6], tz[7]);
  }
  // stats: ms8 / zq for this wave's 8 channels
  #pragma unroll
  for (int i = 0; i < 8; i++) {
    float a = wsum(ms8[i]);
    if (lane == 0) unsafeAtomicAdd(&gms[8 * s + i], a);
  }
  #pragma unroll
  for (int i = 0; i < 8; i++) {
    float b = wsum(zq[i]);
    if (lane == 0) unsafeAtomicAdd(&gzq[8 * s + i], b);
  }
}

// layer-2 BN: zs_j = w1b[:,j]·ms + E*b1b_j; A2d = A2*sign(g1b); zero ms/zq
__global__ void k_fin2(float* __restrict__ ms, float* __restrict__ zq,
    const float* __restrict__ w1b, const float* __restrict__ b1b,
    const float* __restrict__ g1b, const float* __restrict__ be1b,
    float* __restrict__ A2d, float* __restrict__ C2) {
  __shared__ float sm[32];
  int j = threadIdx.x;  // 32 threads
  sm[j] = ms[j];
  __syncthreads();
  float zs = EF * b1b[j];
  #pragma unroll
  for (int k = 0; k < 32; k++) zs = fmaf(w1b[k * 32 + j], sm[k], zs);
  const float invE = 1.f / EF;
  float mu = zs * invE;
  float var = fmaxf(zq[j] * invE - mu * mu, 0.f);
  float A = g1b[j] * rsqrtf(var + 1e-5f);
  float C = be1b[j] - mu * A;
  float d = (g1b[j] >= 0.f) ? 1.f : -1.f;
  A2d[j] = A * d; C2[j] = C;
  ms[j] = 0.f; zq[j] = 0.f;
}

// BN finalize: a = g*rsqrt(var+eps), c = be - mu*a; zero sums for reuse
__global__ void k_finalize(float* __restrict__ sum, float* __restrict__ ssq,
                           const float* __restrict__ g, const float* __restrict__ be,
                           float inv_n, int ncols, float* __restrict__ a, float* __restrict__ c) {
  int j = threadIdx.x;
  if (j < ncols) {
    float mu = sum[j] * inv_n;
    float var = fmaxf(ssq[j] * inv_n - mu * mu, 0.f);
    float s = rsqrtf(var + 1e-5f) * g[j];
    a[j] = s; c[j] = be[j] - mu * s;
    sum[j] = 0.f; ssq[j] = 0.f;
  }
}

// ---------- agg finalize + h_pre = [x, agg] @ w2a + b2a (+stats) ----------

__global__ __launch_bounds__(256) void k_hpre2(const float* __restrict__ xp,
    const float* __restrict__ tzb, const int* __restrict__ starts,
    const float* __restrict__ A2d, const float* __restrict__ C2, const float* __restrict__ w2aT,
    float* __restrict__ hpre, float* __restrict__ gsum, float* __restrict__ gssq) {
  __shared__ float red[256];
  const int n = blockIdx.x * 256 + threadIdx.x;
  float h[32], hh[32];
  #pragma unroll
  for (int j = 0; j < 32; j++) h[j] = 0.f;
  if (n < NN) {
    float xv[11];
    loadrow(xp, n, xv);
    const int dg = starts[n + 1] - starts[n];
    float av[32];
    if (dg > 0) {
      const float4* tp = reinterpret_cast<const float4*>(tzb + (size_t)n * 32);
      #pragma unroll
      for (int j = 0; j < 8; j++) {
        float4 v = tp[j];
        av[4 * j]     = fmaxf(0.f, fmaf(A2d[4 * j],     v.x, C2[4 * j]));
        av[4 * j + 1] = fmaxf(0.f, fmaf(A2d[4 * j + 1], v.y, C2[4 * j + 1]));
        av[4 * j + 2] = fmaxf(0.f, fmaf(A2d[4 * j + 2], v.z, C2[4 * j + 2]));
        av[4 * j + 3] = fmaxf(0.f, fmaf(A2d[4 * j + 3], v.w, C2[4 * j + 3]));
      }
    } else {
      #pragma unroll
      for (int j = 0; j < 32; j++) av[j] = 0.f;
    }
    #pragma unroll
    for (int j = 0; j < 32; j++) {
      const float* wr = w2aT + j * 44;
      float acc = wr[43];
      #pragma unroll
      for (int k = 0; k < 11; k++) acc = fmaf(xv[k], wr[k], acc);
      #pragma unroll
      for (int k = 0; k < 32; k++) acc = fmaf(av[k], wr[11 + k], acc);
      h[j] = acc;
    }
    float4* hp = reinterpret_cast<float4*>(hpre + (size_t)n * 32);
    #pragma unroll
    for (int j = 0; j < 8; j++)
      hp[j] = make_float4(h[4 * j], h[4 * j + 1], h[4 * j + 2], h[4 * j + 3]);
  }
  #pragma unroll
  for (int j = 0; j < 32; j++) hh[j] = h[j] * h[j];
  reduce64(h, hh, red, gsum, gssq);
}

// comb = relu(relu(bn(h_pre)) @ w2b + b2b) -> xp col 10
__global__ __launch_bounds__(256) void k_comb(const float* __restrict__ hpre,
    const float* __restrict__ a3, const float* __restrict__ c3,
    const float* __restrict__ w2b, const float* __restrict__ b2b, float* __restrict__ xp) {
  const int n = blockIdx.x * 256 + threadIdx.x;
  if (n >= NN) return;
  const float4* hp = reinterpret_cast<const float4*>(hpre + (size_t)n * 32);
  float acc = b2b[0];
  #pragma unroll
  for (int j = 0; j < 8; j++) {
    float4 v = hp[j];
    acc += fmaxf(0.f, fmaf(v.x, a3[4 * j],     c3[4 * j]))     * w2b[4 * j];
    acc += fmaxf(0.f, fmaf(v.y, a3[4 * j + 1], c3[4 * j + 1])) * w2b[4 * j + 1];
    acc += fmaxf(0.f, fmaf(v.z, a3[4 * j + 2], c3[4 * j + 2])) * w2b[4 * j + 2];
    acc += fmaxf(0.f, fmaf(v.w, a3[4 * j + 3], c3[4 * j + 3])) * w2b[4 * j + 3];
  }
  xp[(size_t)n * 12 + 10] = fmaxf(acc, 0.f);
}

// ---------- power MLP ----------

// yp = x @ wpa + bpa : store to ybuf + stats
__global__ __launch_bounds__(256) void k_p5(const float* __restrict__ xp, const float* __restrict__ wpaT,
                                            float* __restrict__ ybuf,
                                            float* __restrict__ gsum, float* __restrict__ gssq) {
  __shared__ float red[256];
  const int n = blockIdx.x * 256 + threadIdx.x;
  float y[32], yy[32];
  #pragma unroll
  for (int j = 0; j < 32; j++) y[j] = 0.f;
  if (n < NN) {
    float xv[11];
    loadrow(xp, n, xv);
    #pragma unroll
    for (int j = 0; j < 32; j++) {
      const float* wr = wpaT + j * 12;
      float acc = wr[11];
      #pragma unroll
      for (int k = 0; k < 11; k++) acc = fmaf(xv[k], wr[k], acc);
      y[j] = acc;
    }
    float4* yp = reinterpret_cast<float4*>(ybuf + (size_t)n * 32);
    #pragma unroll
    for (int j = 0; j < 8; j++)
      yp[j] = make_float4(y[4 * j], y[4 * j + 1], y[4 * j + 2], y[4 * j + 3]);
  }
  #pragma unroll
  for (int j = 0; j < 32; j++) yy[j] = y[j] * y[j];
  reduce64(y, yy, red, gsum, gssq);
}

// yq = relu(bn(yp)) @ wpb + bpb : store + scalar stats (reads stored yp)
__global__ __launch_bounds__(256) void k_p6(const float* __restrict__ ybuf,
    const float* __restrict__ a4, const float* __restrict__ c4,
    const float* __restrict__ wpb, const float* __restrict__ bpb,
    float* __restrict__ yq, float* __restrict__ gsum, float* __restrict__ gssq) {
  __shared__ float red[8];
  const int n = blockIdx.x * 256 + threadIdx.x;
  float sum = 0.f, ssq = 0.f;
  if (n < NN) {
    const float4* yp = reinterpret_cast<const float4*>(ybuf + (size_t)n * 32);
    float q = bpb[0];
    #pragma unroll
    for (int j = 0; j < 8; j++) {
      float4 v = yp[j];
      q = fmaf(fmaxf(0.f, fmaf(v.x, a4[4 * j],     c4[4 * j])),     wpb[4 * j],     q);
      q = fmaf(fmaxf(0.f, fmaf(v.y, a4[4 * j + 1], c4[4 * j + 1])), wpb[4 * j + 1], q);
      q = fmaf(fmaxf(0.f, fmaf(v.z, a4[4 * j + 2], c4[4 * j + 2])), wpb[4 * j + 2], q);
      q = fmaf(fmaxf(0.f, fmaf(v.w, a4[4 * j + 3], c4[4 * j + 3])), wpb[4 * j + 3], q);
    }
    yq[n] = q;
    sum = q; ssq = q * q;
  }
  float s = wsum(sum), qq = wsum(ssq);
  const int wid = threadIdx.x >> 6, lane = threadIdx.x & 63;
  if (lane == 0) { red[wid] = s; red[4 + wid] = qq; }
  __syncthreads();
  if (threadIdx.x == 0) {
    unsafeAtomicAdd(&gsum[0], red[0] + red[1] + red[2] + red[3]);
    unsafeAtomicAdd(&gssq[0], red[4] + red[5] + red[6] + red[7]);
  }
}

__global__ __launch_bounds__(256) void k_p7(const float* __restrict__ yq,
    const float* __restrict__ a5, const float* __restrict__ c5, float* __restrict__ out) {
  int n = blockIdx.x * 256 + threadIdx.x;
  if (n < NN) out[n] = fmaxf(0.f, fmaf(yq[n], a5[0], c5[0]));
}

// ---------- host launch ----------

extern "C" void kernel_launch(void* const* d_in, const int* in_sizes, int n_in,
                              void* d_out, int out_size, void* d_ws, size_t ws_size,
                              hipStream_t stream) {
  const float* x    = (const float*)d_in[0];
  const float* ea   = (const float*)d_in[1];
  const int*   ei   = (const int*)d_in[2];
  const int*   srcp = ei;
  const int*   dstp = ei + EE;
  const float* w1a = (const float*)d_in[3],  *b1a = (const float*)d_in[4];
  const float* g1a = (const float*)d_in[5],  *be1a = (const float*)d_in[6];
  const float* w1b = (const float*)d_in[7],  *b1b = (const float*)d_in[8];
  const float* g1b = (const float*)d_in[9],  *be1b = (const float*)d_in[10];
  const float* w2a = (const float*)d_in[11], *b2a = (const float*)d_in[12];
  const float* g2a = (const float*)d_in[13], *be2a = (const float*)d_in[14];
  const float* w2b = (const float*)d_in[15], *b2b = (const float*)d_in[16];
  const float* wpa = (const float*)d_in[17], *bpa = (const float*)d_in[18];
  const float* gpa = (const float*)d_in[19], *bepa = (const float*)d_in[20];
  const float* wpb = (const float*)d_in[21], *bpb = (const float*)d_in[22];
  const float* gpb = (const float*)d_in[23], *bepb = (const float*)d_in[24];

  size_t off = 0;
  char* base = (char*)d_ws;
  auto alloc = [&](size_t bytes) -> void* {
    void* p = base + off;
    off += (bytes + 255) & ~(size_t)255;
    return p;
  };
  float* stats = (float*)alloc(2048);
  float* coef  = (float*)alloc(2048);
  float* mom   = (float*)alloc(512);
  float* cmom  = (float*)alloc(256);
  float* w1f   = (float*)alloc(16 * 32 * 4);
  float* wexy  = (float*)alloc(64 * 4);
  float* w2tf  = (float*)alloc(32 * 32 * 4);
  float* b1bf  = (float*)alloc(256);
  float* w2aT  = (float*)alloc(32 * 44 * 4);
  float* wpaT  = (float*)alloc(32 * 12 * 4);
  int*   cnt    = (int*)alloc(NN * 4);
  int*   deg    = (int*)alloc(NN * 4);
  float* sea    = (float*)alloc((size_t)NN * 2 * 4);
  int*   starts = (int*)alloc((NN + 1) * 4);
  int*   fill   = (int*)alloc(NN * 4);
  int4*  edg    = (int4*)alloc((size_t)EE * 16);
  float* xp     = (float*)alloc((size_t)NN * 12 * 4);
  float* P      = (float*)alloc((size_t)NN * 32 * 4);
  float* tzb    = (float*)alloc((size_t)NN * 32 * 4);
  float* hpre   = (float*)alloc((size_t)NN * 32 * 4);
  float* yq     = (float*)alloc(NN * 4);

  float *MS2  = stats,       *ZQ2  = stats + 32;
  float *SUM3 = stats + 64,  *SSQ3 = stats + 96;
  float *SUM4 = stats + 128, *SSQ4 = stats + 160;
  float *SUM5 = stats + 192, *SSQ5 = stats + 224;
  float *A2d = coef,       *C2 = coef + 32;
  float *A3  = coef + 64,  *C3 = coef + 96;
  float *A4  = coef + 128, *C4 = coef + 160;
  float *A5  = coef + 192, *C5 = coef + 224;

  hipMemsetAsync(stats, 0, 2048, stream);
  hipMemsetAsync(mom, 0, 512 + 256, stream);   // mom + cmom
  hipMemsetAsync(cnt, 0, NN * 4, stream);
  hipMemsetAsync(deg, 0, NN * 4, stream);
  hipMemsetAsync(sea, 0, (size_t)NN * 2 * 4, stream);

  const int GN = (NN + 255) / 256;          // 391
  const int GW = (NN + 31) / 32;            // 3125 blocks: 32 nodes x 2 parity x 4 channel-slice waves
  const int GE4 = (EE / 4 + 255) / 256;     // 3125

  k_wprep  <<<1, 256, 0, stream>>>(w1b, b1b, g1b, w2a, b2a, wpa, bpa, w2tf, b1bf, w2aT, wpaT);
  k_prep   <<<GE4, 256, 0, stream>>>(dstp, srcp, ea, cnt, deg, sea, cmom);
  k_scan   <<<1, 1024, 0, stream>>>(cnt, starts, fill);
  k_scatter<<<GE4, 256, 0, stream>>>(dstp, srcp, ea, fill, edg);
  k_xp     <<<GN, 256, 0, stream>>>(x, xp);

  const float invN = 1.f / (float)NN;
  for (int c = 0; c < 3; c++) {
    k_mom     <<<GN, 256, 0, stream>>>(xp, deg, sea, mom);
    k_fin1    <<<1, 32, 0, stream>>>(mom, cmom, w1a, b1a, g1a, be1a, w1f, wexy);
    k_P       <<<GN, 256, 0, stream>>>(xp, w1f, P);
    k_fusedagg<<<GW, 256, 0, stream>>>(starts, edg, P, wexy, w2tf, b1bf, tzb, MS2, ZQ2);
    k_fin2    <<<1, 32, 0, stream>>>(MS2, ZQ2, w1b, b1b, g1b, be1b, A2d, C2);
    k_hpre2   <<<GN, 256, 0, stream>>>(xp, tzb, starts, A2d, C2, w2aT, hpre, SUM3, SSQ3);
    k_finalize<<<1, 32, 0, stream>>>(SUM3, SSQ3, g2a, be2a, invN, 32, A3, C3);
    k_comb    <<<GN, 256, 0, stream>>>(hpre, A3, C3, w2b, b2b, xp);
  }

  k_p5      <<<GN, 256, 0, stream>>>(xp, wpaT, hpre, SUM4, SSQ4);
  k_finalize<<<1, 32, 0, stream>>>(SUM4, SSQ4, gpa, bepa, invN, 32, A4, C4);
  k_p6      <<<GN, 256, 0, stream>>>(hpre, A4, C4, wpb, bpb, yq, SUM5, SSQ5);
  k_finalize<<<1, 32, 0, stream>>>(SUM5, SSQ5, gpb, bepb, invN, 1, A5, C5);
  k_p7      <<<GN, 256, 0, stream>>>(yq, A5, C5, (float*)d_out);
}